// Round 19
// baseline (607.945 us; speedup 1.0000x reference)
//
#include <hip/hip_runtime.h>
#include <hip/hip_bf16.h>
#include <stdint.h>

typedef unsigned short u16;
using f32x4  = __attribute__((ext_vector_type(4))) float;
using bf16x8 = __attribute__((ext_vector_type(8))) __bf16;
using u32x4  = __attribute__((ext_vector_type(4))) uint32_t;
using u16x4  = __attribute__((ext_vector_type(4))) unsigned short;
using u16x8  = __attribute__((ext_vector_type(8))) unsigned short;

#define S_LEN 2048
#define DM    2048
#define NH    16
#define QLR   1536
#define KVLR  512
#define DNOPE 128
#define DROPE 64
#define DVAL  128
#define FFD   8192

static __device__ __forceinline__ float bf2f(u16 u) {
    union { uint32_t i; float f; } v; v.i = ((uint32_t)u) << 16; return v.f;
}
static __device__ __forceinline__ u16 f2bf(float f) {
    union { float f; uint32_t i; } v; v.f = f;
    uint32_t x = v.i;
    return (u16)((x + 0x7FFF + ((x >> 16) & 1)) >> 16);  // RNE
}
static __device__ __forceinline__ void gload16(const u16* g, const u16* l) {
    __builtin_amdgcn_global_load_lds(
        (const __attribute__((address_space(1))) void*)g,
        (__attribute__((address_space(3))) void*)l, 16, 0, 0);
}

// ---------------- weight transposes (early: 4 jobs, one launch)
struct TWJob { const float* src; u16* dst; int R, C, xt, start; };
struct TWJobs { TWJob j[4]; };

__global__ __launch_bounds__(256)
void transpose_all(TWJobs jobs)
{
    __shared__ __align__(16) u16 tile[64][68];
    const int bid = blockIdx.x;
    int e = 0;
#pragma unroll
    for (int i = 1; i < 4; ++i) e = (bid >= jobs.j[i].start) ? i : e;
    const float* src = jobs.j[e].src;
    u16* dst = jobs.j[e].dst;
    const int R = jobs.j[e].R, C = jobs.j[e].C;
    const int local = bid - jobs.j[e].start;
    const int c0 = (local % jobs.j[e].xt) * 64;
    const int r0 = (local / jobs.j[e].xt) * 64;
    const int t = threadIdx.x;
#pragma unroll
    for (int i = 0; i < 4; ++i) {
        int idx = i * 256 + t;
        int r = idx >> 4, c4 = idx & 15;
        float4 v = *reinterpret_cast<const float4*>(&src[(size_t)(r0 + r) * C + c0 + c4 * 4]);
        u16x4 b; b[0] = f2bf(v.x); b[1] = f2bf(v.y); b[2] = f2bf(v.z); b[3] = f2bf(v.w);
        *reinterpret_cast<u16x4*>(&tile[r][c4 * 4]) = b;
    }
    __syncthreads();
#pragma unroll
    for (int i = 0; i < 4; ++i) {
        int idx = i * 256 + t;
        int rr = idx >> 4, k4 = idx & 15;
        u16x4 o;
#pragma unroll
        for (int j = 0; j < 4; ++j) o[j] = tile[k4 * 4 + j][rr];
        *reinterpret_cast<u16x4*>(&dst[(size_t)(c0 + rr) * R + r0 + k4 * 4]) = o;
    }
}

// ---------------- RMS norm + optional f32 copy of input (x2 = in)
__global__ __launch_bounds__(256)
void rms_norm_copy(const float* __restrict__ in, int width,
                   const float* __restrict__ scale, u16* __restrict__ out,
                   float* __restrict__ copy_out)
{
    const int row = blockIdx.x;
    const int t = threadIdx.x;
    float ss = 0.f;
    for (int c = t; c < width; c += 256) {
        float v = in[(size_t)row * width + c];
        ss += v * v;
    }
#pragma unroll
    for (int o = 32; o > 0; o >>= 1) ss += __shfl_xor(ss, o);
    __shared__ float red[4];
    if ((t & 63) == 0) red[t >> 6] = ss;
    __syncthreads();
    float inv = rsqrtf((red[0] + red[1] + red[2] + red[3]) / (float)width + 1e-6f);
    for (int c = t; c < width; c += 256) {
        float v = in[(size_t)row * width + c];
        out[(size_t)row * width + c] = f2bf(v * inv * scale[c]);
        copy_out[(size_t)row * width + c] = v;
    }
}

// ---------------- RMS norm + bias epilogue (outf = in + bd): pre-ffn
__global__ __launch_bounds__(256)
void rms_norm_bias(const float* __restrict__ in, int width,
                   const float* __restrict__ scale, u16* __restrict__ out,
                   const float* __restrict__ bd, float* __restrict__ outf)
{
    const int row = blockIdx.x;
    const int t = threadIdx.x;
    float ss = 0.f;
    for (int c = t; c < width; c += 256) {
        float v = in[(size_t)row * width + c];
        ss += v * v;
    }
#pragma unroll
    for (int o = 32; o > 0; o >>= 1) ss += __shfl_xor(ss, o);
    __shared__ float red[4];
    if ((t & 63) == 0) red[t >> 6] = ss;
    __syncthreads();
    float inv = rsqrtf((red[0] + red[1] + red[2] + red[3]) / (float)width + 1e-6f);
    for (int c = t; c < width; c += 256) {
        float v = in[(size_t)row * width + c];
        out[(size_t)row * width + c] = f2bf(v * inv * scale[c]);
        outf[(size_t)row * width + c] = v + bd[c];
    }
}

// ---------------- dual RMS norm (f32 in): y selects job
__global__ __launch_bounds__(256)
void rms_norm2(const float* __restrict__ inA, int strideA, int widthA,
               const float* __restrict__ scaleA, u16* __restrict__ outA, int ostrA,
               const float* __restrict__ inB, int strideB, int widthB,
               const float* __restrict__ scaleB, u16* __restrict__ outB, int ostrB)
{
    const float* in   = blockIdx.y ? inB : inA;
    const float* scale= blockIdx.y ? scaleB : scaleA;
    u16* out          = blockIdx.y ? outB : outA;
    const int stride  = blockIdx.y ? strideB : strideA;
    const int width   = blockIdx.y ? widthB : widthA;
    const int ostr    = blockIdx.y ? ostrB : ostrA;
    const int row = blockIdx.x;
    const int t = threadIdx.x;
    float ss = 0.f;
    for (int c = t; c < width; c += 256) {
        float v = in[(size_t)row * stride + c];
        ss += v * v;
    }
#pragma unroll
    for (int o = 32; o > 0; o >>= 1) ss += __shfl_xor(ss, o);
    __shared__ float red[4];
    if ((t & 63) == 0) red[t >> 6] = ss;
    __syncthreads();
    float inv = rsqrtf((red[0] + red[1] + red[2] + red[3]) / (float)width + 1e-6f);
    for (int c = t; c < width; c += 256) {
        float v = in[(size_t)row * stride + c];
        out[(size_t)row * ostr + c] = f2bf(v * inv * scale[c]);
    }
}

// ---------------- RoPE + V-transpose merged
__global__ __launch_bounds__(256)
void rope_tv(u16* __restrict__ q, const float* __restrict__ kva, u16* __restrict__ kr,
             const u16* __restrict__ kv, u16* __restrict__ vt)
{
    const int bid = blockIdx.x;
    const int t = threadIdx.x;
    if (bid < S_LEN) {
        const int s = bid;
        for (int idx = t; idx < 544; idx += 256) {
            int d = idx & 31;
            float invf = powf(10000.f, -(float)(2 * d) / 64.f);
            float ang = (float)s * invf;
            float cs = cosf(ang), sn = sinf(ang);
            if (idx < 512) {
                int hh = idx >> 5;
                u16* base = q + ((size_t)s * NH + hh) * 192 + 128;
                float x1 = bf2f(base[d]), x2 = bf2f(base[d + 32]);
                base[d]      = f2bf(x1 * cs - x2 * sn);
                base[d + 32] = f2bf(x2 * cs + x1 * sn);
            } else {
                const float* kb = kva + (size_t)s * 576 + 512;
                float x1 = kb[d], x2 = kb[d + 32];
                kr[(size_t)s * 64 + d]      = f2bf(x1 * cs - x2 * sn);
                kr[(size_t)s * 64 + d + 32] = f2bf(x2 * cs + x1 * sn);
            }
        }
        return;
    }
    __shared__ __align__(16) u16 tile[64][76];
    const int t2 = bid - S_LEN;
    const int s0 = (t2 & 31) * 64;
    const int d0 = ((t2 >> 5) & 1) * 64;
    const int h  = t2 >> 6;
#pragma unroll
    for (int i = 0; i < 2; ++i) {
        int idx = i * 256 + t;
        int s = idx >> 3, c8 = idx & 7;
        u16x8 v = *reinterpret_cast<const u16x8*>(kv + (size_t)(s0 + s) * (NH * 256) + h * 256 + 128 + d0 + c8 * 8);
        u16x4 lo, hi;
#pragma unroll
        for (int j = 0; j < 4; ++j) { lo[j] = v[j]; hi[j] = v[4 + j]; }
        *reinterpret_cast<u16x4*>(&tile[s][c8 * 8])     = lo;
        *reinterpret_cast<u16x4*>(&tile[s][c8 * 8 + 4]) = hi;
    }
    __syncthreads();
#pragma unroll
    for (int i = 0; i < 4; ++i) {
        int idx = i * 256 + t;
        int d = idx >> 4, s4 = idx & 15;
        u16x4 o;
#pragma unroll
        for (int j = 0; j < 4; ++j) o[j] = tile[s4 * 4 + j][d];
        *reinterpret_cast<u16x4*>(&vt[(size_t)(h * 128 + d0 + d) * S_LEN + s0 + s4 * 4]) = o;
    }
}

// ---------------- dual-job 128x128 BK=64 TN bf16 GEMM — qa/kva path
struct GJob { const u16* A; const u16* BT; void* out; int N, K, yCount, zCount; };

template<int EPI>
__global__ __launch_bounds__(256)
void gemm_bt2(GJob j0, GJob j1)
{
    __shared__ __align__(16) u16 As[128 * 64];
    __shared__ __align__(16) u16 Bs[128 * 64];
    const int t = threadIdx.x;
    const int lane = t & 63;
    const int w = t >> 6;
    const int wr = w >> 1, wc = w & 1;
    const int li = lane & 15;
    const int lg = lane >> 4;

    const int gx = gridDim.x;
    int nwg = gx * gridDim.y;
    int bid = blockIdx.y * gx + blockIdx.x;
    bid = (bid & 7) * (nwg >> 3) + (bid >> 3);
    const int m0 = (bid % gx) * 128;
    int yy = bid / gx;

    const int j0span = j0.yCount * j0.zCount;
    const GJob& J = (yy < j0span) ? j0 : j1;
    if (yy >= j0span) yy -= j0span;
    const int ntile = yy % J.yCount;
    const int z = yy / J.yCount;
    const int n0 = ntile * 128;
    const int N = J.N, K = J.K;

    const int nktt = K >> 6;
    const int nz = J.zCount;
    const int qq = nktt / nz, rr = nktt % nz;
    const int kt0 = z * qq + (z < rr ? z : rr);
    const int ktEnd = kt0 + qq + (z < rr ? 1 : 0);

    const int srow = w * 32 + (lane >> 3);
    const int scol = (((lane & 7) ^ (lane >> 3)) << 3);
    const u16* ag = J.A  + (size_t)(m0 + srow) * K + scol;
    const u16* bg = J.BT + (size_t)(n0 + srow) * K + scol;

    f32x4 acc[4][4];
#pragma unroll
    for (int m = 0; m < 4; ++m)
#pragma unroll
        for (int n = 0; n < 4; ++n)
            acc[m][n] = f32x4{0.f, 0.f, 0.f, 0.f};

    for (int kt = kt0; kt < ktEnd; ++kt) {
        const int k0 = kt << 6;
        __syncthreads();
#pragma unroll
        for (int i = 0; i < 4; ++i) {
            gload16(ag + (size_t)i * 8 * K + k0, As + (w * 32 + i * 8) * 64);
            gload16(bg + (size_t)i * 8 * K + k0, Bs + (w * 32 + i * 8) * 64);
        }
        __syncthreads();
#pragma unroll
        for (int kk = 0; kk < 2; ++kk) {
            const int csw = (kk * 32 + lg * 8) ^ ((li & 7) << 3);
            bf16x8 af[4], bfr[4];
#pragma unroll
            for (int m = 0; m < 4; ++m)
                af[m] = *reinterpret_cast<const bf16x8*>(As + (wr * 64 + m * 16 + li) * 64 + csw);
#pragma unroll
            for (int n = 0; n < 4; ++n)
                bfr[n] = *reinterpret_cast<const bf16x8*>(Bs + (wc * 64 + n * 16 + li) * 64 + csw);
#pragma unroll
            for (int m = 0; m < 4; ++m)
#pragma unroll
                for (int n = 0; n < 4; ++n)
                    acc[m][n] = __builtin_amdgcn_mfma_f32_16x16x32_bf16(af[m], bfr[n], acc[m][n], 0, 0, 0);
        }
    }

#pragma unroll
    for (int m = 0; m < 4; ++m) {
        const int row = m0 + wr * 64 + m * 16 + lg * 4;
#pragma unroll
        for (int n = 0; n < 4; ++n) {
            const int col = n0 + wc * 64 + n * 16 + li;
            if (col < N) {
#pragma unroll
                for (int r2 = 0; r2 < 4; ++r2) {
                    float v = acc[m][n][r2];
                    size_t idx = (size_t)(row + r2) * N + col;
                    if (EPI == 0) ((u16*)J.out)[idx] = f2bf(v);
                    else          unsafeAtomicAdd((float*)J.out + idx, v);
                }
            }
        }
    }
}

// ---------------- dual-job 256x128 BK=64 bf16 GEMM, 8 waves — qb/kvb path
struct BJob { const u16* A; const u16* BT; u16* out; int N, K, yCount; };

__global__ __launch_bounds__(512, 4)
void gemm_big2(BJob j0, BJob j1)
{
    __shared__ __align__(16) u16 As[256 * 64];
    __shared__ __align__(16) u16 Bs[128 * 64];
    const int t = threadIdx.x;
    const int lane = t & 63;
    const int w = t >> 6;
    const int wr = w >> 1, wc = w & 1;
    const int li = lane & 15;
    const int lg = lane >> 4;

    const int gx = gridDim.x;
    int nwg = gx * gridDim.y;
    int bid = blockIdx.y * gx + blockIdx.x;
    bid = (bid & 7) * (nwg >> 3) + (bid >> 3);
    const int m0 = (bid % gx) * 256;
    int yy = bid / gx;

    const BJob& J = (yy < j0.yCount) ? j0 : j1;
    if (yy >= j0.yCount) yy -= j0.yCount;
    const int n0 = yy * 128;
    const int N = J.N, K = J.K;

    const int sr = lane >> 3;
    const int scol = (((lane & 7) ^ sr) << 3);
    const u16* ag = J.A  + (size_t)(m0 + w * 8 + sr) * K + scol;
    const u16* bg = J.BT + (size_t)(n0 + w * 8 + sr) * K + scol;
    const u16* lA = As + (w * 8) * 64;
    const u16* lB = Bs + (w * 8) * 64;

    f32x4 acc[4][4];
#pragma unroll
    for (int m = 0; m < 4; ++m)
#pragma unroll
        for (int n = 0; n < 4; ++n)
            acc[m][n] = f32x4{0.f, 0.f, 0.f, 0.f};

    const int nkt = K >> 6;
    for (int kt = 0; kt < nkt; ++kt) {
        const int k0 = kt << 6;
        __syncthreads();
#pragma unroll
        for (int i = 0; i < 4; ++i)
            gload16(ag + (size_t)i * 64 * K + k0, lA + i * 64 * 64);
#pragma unroll
        for (int i = 0; i < 2; ++i)
            gload16(bg + (size_t)i * 64 * K + k0, lB + i * 64 * 64);
        __syncthreads();
        __builtin_amdgcn_s_setprio(1);
#pragma unroll
        for (int kk = 0; kk < 2; ++kk) {
            const int csw = (kk * 32 + lg * 8) ^ ((li & 7) << 3);
            bf16x8 af[4], bfr[4];
#pragma unroll
            for (int m = 0; m < 4; ++m)
                af[m] = *reinterpret_cast<const bf16x8*>(As + (wr * 64 + m * 16 + li) * 64 + csw);
#pragma unroll
            for (int n = 0; n < 4; ++n)
                bfr[n] = *reinterpret_cast<const bf16x8*>(Bs + (wc * 64 + n * 16 + li) * 64 + csw);
#pragma unroll
            for (int m = 0; m < 4; ++m)
#pragma unroll
                for (int n = 0; n < 4; ++n)
                    acc[m][n] = __builtin_amdgcn_mfma_f32_16x16x32_bf16(af[m], bfr[n], acc[m][n], 0, 0, 0);
        }
        __builtin_amdgcn_s_setprio(0);
    }

#pragma unroll
    for (int m = 0; m < 4; ++m) {
        const int row = m0 + wr * 64 + m * 16 + lg * 4;
#pragma unroll
        for (int n = 0; n < 4; ++n) {
            const int col = n0 + wc * 64 + n * 16 + li;
#pragma unroll
            for (int r2 = 0; r2 < 4; ++r2)
                J.out[(size_t)(row + r2) * N + col] = f2bf(acc[m][n][r2]);
        }
    }
}

// ---------------- 256x128 BK=64 TN bf16 GEMM, 8 waves (R9-proven): wo split-K
template<int EPI>
__global__ __launch_bounds__(512, 4)
void gemm_big(const u16* __restrict__ A, const u16* __restrict__ BT,
              void* __restrict__ out, int M, int N, int K,
              const float* __restrict__ bias, const u16* __restrict__ gmul)
{
    __shared__ __align__(16) u16 As[256 * 64];
    __shared__ __align__(16) u16 Bs[128 * 64];
    const int t = threadIdx.x;
    const int lane = t & 63;
    const int w = t >> 6;
    const int wr = w >> 1, wc = w & 1;
    const int li = lane & 15;
    const int lg = lane >> 4;

    const int gx = gridDim.x;
    int nwg = gx * gridDim.y;
    int bid = blockIdx.y * gx + blockIdx.x;
    bid = (bid & 7) * (nwg >> 3) + (bid >> 3);
    const int m0 = (bid % gx) * 256;
    const int n0 = (bid / gx) * 128;

    const int nz = gridDim.z, z = blockIdx.z;
    const int nktt = K >> 6;
    const int qq = nktt / nz, rr = nktt % nz;
    const int kt0 = z * qq + (z < rr ? z : rr);
    const int ktEnd = kt0 + qq + (z < rr ? 1 : 0);

    const int sr = lane >> 3;
    const int scol = (((lane & 7) ^ sr) << 3);
    const u16* ag = A  + (size_t)(m0 + w * 8 + sr) * K + scol;
    const u16* bg = BT + (size_t)(n0 + w * 8 + sr) * K + scol;
    const u16* lA = As + (w * 8) * 64;
    const u16* lB = Bs + (w * 8) * 64;

    f32x4 acc[4][4];
#pragma unroll
    for (int m = 0; m < 4; ++m)
#pragma unroll
        for (int n = 0; n < 4; ++n)
            acc[m][n] = f32x4{0.f, 0.f, 0.f, 0.f};

    for (int kt = kt0; kt < ktEnd; ++kt) {
        const int k0 = kt << 6;
        __syncthreads();
#pragma unroll
        for (int i = 0; i < 4; ++i)
            gload16(ag + (size_t)i * 64 * K + k0, lA + i * 64 * 64);
#pragma unroll
        for (int i = 0; i < 2; ++i)
            gload16(bg + (size_t)i * 64 * K + k0, lB + i * 64 * 64);
        __syncthreads();
        __builtin_amdgcn_s_setprio(1);
#pragma unroll
        for (int kk = 0; kk < 2; ++kk) {
            const int csw = (kk * 32 + lg * 8) ^ ((li & 7) << 3);
            bf16x8 af[4], bfr[4];
#pragma unroll
            for (int m = 0; m < 4; ++m)
                af[m] = *reinterpret_cast<const bf16x8*>(As + (wr * 64 + m * 16 + li) * 64 + csw);
#pragma unroll
            for (int n = 0; n < 4; ++n)
                bfr[n] = *reinterpret_cast<const bf16x8*>(Bs + (wc * 64 + n * 16 + li) * 64 + csw);
#pragma unroll
            for (int m = 0; m < 4; ++m)
#pragma unroll
                for (int n = 0; n < 4; ++n)
                    acc[m][n] = __builtin_amdgcn_mfma_f32_16x16x32_bf16(af[m], bfr[n], acc[m][n], 0, 0, 0);
        }
        __builtin_amdgcn_s_setprio(0);
    }

#pragma unroll
    for (int m = 0; m < 4; ++m) {
        const int row = m0 + wr * 64 + m * 16 + lg * 4;
#pragma unroll
        for (int n = 0; n < 4; ++n) {
            const int col = n0 + wc * 64 + n * 16 + li;
#pragma unroll
            for (int r2 = 0; r2 < 4; ++r2) {
                float v = acc[m][n][r2];
                size_t idx = (size_t)(row + r2) * N + col;
                if (EPI == 0) ((u16*)out)[idx] = f2bf(v);
                else          unsafeAtomicAdd((float*)out + idx, v);
            }
        }
    }
}

// ---------------- wd GEMM with fused A = silu(g)*u (reg-staged A, gload B), split-K atomics
__global__ __launch_bounds__(512, 4)
void gemm_wd(const u16* __restrict__ G, const u16* __restrict__ U,
             const u16* __restrict__ BT, float* __restrict__ out,
             int M, int N, int K)
{
    __shared__ __align__(16) u16 As[256 * 64];
    __shared__ __align__(16) u16 Bs[128 * 64];
    const int t = threadIdx.x;
    const int lane = t & 63;
    const int w = t >> 6;
    const int wr = w >> 1, wc = w & 1;
    const int li = lane & 15;
    const int lg = lane >> 4;

    const int gx = gridDim.x;
    int nwg = gx * gridDim.y;
    int bid = blockIdx.y * gx + blockIdx.x;
    bid = (bid & 7) * (nwg >> 3) + (bid >> 3);
    const int m0 = (bid % gx) * 256;
    const int n0 = (bid / gx) * 128;

    const int nz = gridDim.z, z = blockIdx.z;
    const int nktt = K >> 6;
    const int qq = nktt / nz, rr = nktt % nz;
    const int kt0 = z * qq + (z < rr ? z : rr);
    const int ktEnd = kt0 + qq + (z < rr ? 1 : 0);

    const int sr = lane >> 3;
    const int scol = (((lane & 7) ^ sr) << 3);
    const u16* gg = G  + (size_t)(m0 + w * 8 + sr) * K + scol;
    const u16* ug = U  + (size_t)(m0 + w * 8 + sr) * K + scol;
    const u16* bg = BT + (size_t)(n0 + w * 8 + sr) * K + scol;
    u16* lA = As + (w * 8) * 64;            // wave-uniform base; lane writes at +lane*8 (16B)
    const u16* lB = Bs + (w * 8) * 64;

    f32x4 acc[4][4];
#pragma unroll
    for (int m = 0; m < 4; ++m)
#pragma unroll
        for (int n = 0; n < 4; ++n)
            acc[m][n] = f32x4{0.f, 0.f, 0.f, 0.f};

    for (int kt = kt0; kt < ktEnd; ++kt) {
        const int k0 = kt << 6;
        __syncthreads();
        // B: async gload to LDS (linear dest, pre-swizzled source)
#pragma unroll
        for (int i = 0; i < 2; ++i)
            gload16(bg + (size_t)i * 64 * K + k0, lB + i * 64 * 64);
        // A: reg-load g,u at the same pre-swizzled addresses, multiply, ds_write to the
        // exact slot gload16 would have written (lane L -> base + L*16B)
        u16x8 gr[4], ur[4];
#pragma unroll
        for (int i = 0; i < 4; ++i) {
            gr[i] = *reinterpret_cast<const u16x8*>(gg + (size_t)i * 64 * K + k0);
            ur[i] = *reinterpret_cast<const u16x8*>(ug + (size_t)i * 64 * K + k0);
        }
#pragma unroll
        for (int i = 0; i < 4; ++i) {
            u16x8 hv;
#pragma unroll
            for (int j = 0; j < 8; ++j) hv[j] = f2bf(bf2f(gr[i][j]) * bf2f(ur[i][j]));
            *reinterpret_cast<u16x8*>(lA + i * 64 * 64 + lane * 8) = hv;
        }
        __syncthreads();
        __builtin_amdgcn_s_setprio(1);
#pragma unroll
        for (int kk = 0; kk < 2; ++kk) {
            const int csw = (kk * 32 + lg * 8) ^ ((li & 7) << 3);
            bf16x8 af[4], bfr[4];
#pragma unroll
            for (int m = 0; m < 4; ++m)
                af[m] = *reinterpret_cast<const bf16x8*>(As + (wr * 64 + m * 16 + li) * 64 + csw);
#pragma unroll
            for (int n = 0; n < 4; ++n)
                bfr[n] = *reinterpret_cast<const bf16x8*>(Bs + (wc * 64 + n * 16 + li) * 64 + csw);
#pragma unroll
            for (int m = 0; m < 4; ++m)
#pragma unroll
                for (int n = 0; n < 4; ++n)
                    acc[m][n] = __builtin_amdgcn_mfma_f32_16x16x32_bf16(af[m], bfr[n], acc[m][n], 0, 0, 0);
        }
        __builtin_amdgcn_s_setprio(0);
    }

#pragma unroll
    for (int m = 0; m < 4; ++m) {
        const int row = m0 + wr * 64 + m * 16 + lg * 4;
#pragma unroll
        for (int n = 0; n < 4; ++n) {
            const int col = n0 + wc * 64 + n * 16 + li;
#pragma unroll
            for (int r2 = 0; r2 < 4; ++r2)
                unsafeAtomicAdd(out + (size_t)(row + r2) * N + col, acc[m][n][r2]);
        }
    }
}

// ---------------- gate+up co-scheduled GEMM (R16-proven form)
__global__ __launch_bounds__(512, 4)
void gemm_gu(const u16* __restrict__ A, const u16* __restrict__ BgT, const u16* __restrict__ BuT,
             u16* __restrict__ gout, u16* __restrict__ uout, int M, int N, int K,
             const float* __restrict__ bg, const float* __restrict__ bu)
{
    __shared__ __align__(16) u16 As[256 * 64];
    __shared__ __align__(16) u16 Bs[128 * 64];
    const int t = threadIdx.x;
    const int lane = t & 63;
    const int w = t >> 6;
    const int wr = w >> 1, wc = w & 1;
    const int li = lane & 15;
    const int lg = lane >> 4;
    const int isUp = blockIdx.z;

    const u16* BT = isUp ? BuT : BgT;
    const float* bias = isUp ? bu : bg;
    u16* out = isUp ? uout : gout;

    const int gx = gridDim.x;
    int nwg = gx * gridDim.y;
    int bid = blockIdx.y * gx + blockIdx.x;
    bid = (bid & 7) * (nwg >> 3) + (bid >> 3);
    const int m0 = (bid % gx) * 256;
    const int n0 = (bid / gx) * 128;

    const int sr = lane >> 3;
    const int scol = (((lane & 7) ^ sr) << 3);
    const u16* ag = A  + (size_t)(m0 + w * 8 + sr) * K + scol;
    const u16* bgp = BT + (size_t)(n0 + w * 8 + sr) * K + scol;
    const u16* lA = As + (w * 8) * 64;
    const u16* lB = Bs + (w * 8) * 64;

    f32x4 acc[4][4];
#pragma unroll
    for (int m = 0; m < 4; ++m)
#pragma unroll
        for (int n = 0; n < 4; ++n)
            acc[m][n] = f32x4{0.f, 0.f, 0.f, 0.f};

    const int nkt = K >> 6;
    for (int kt = 0; kt < nkt; ++kt) {
        const int k0 = kt << 6;
        __syncthreads();
#pragma unroll
        for (int i = 0; i < 4; ++i)
            gload16(ag + (size_t)i * 64 * K + k0, lA + i * 64 * 64);
#pragma unroll
        for (int i = 0; i < 2; ++i)
            gload16(bgp + (size_t)i * 64 * K + k0, lB + i * 64 * 64);
        __syncthreads();
        __builtin_amdgcn_s_setprio(1);
#pragma unroll
        for (int kk = 0; kk < 2; ++kk) {
            const int csw = (kk * 32 + lg * 8) ^ ((li & 7) << 3);
            bf16x8 af[4], bfr[4];
#pragma unroll
            for (int m = 0; m < 4; ++m)
                af[m] = *reinterpret_cast<const bf16x8*>(As + (wr * 64 + m * 16 + li) * 64 + csw);
#pragma unroll
            for (int n = 0; n < 4; ++n)
                bfr[n] = *reinterpret_cast<const bf16x8*>(Bs + (wc * 64 + n * 16 + li) * 64 + csw);
#pragma unroll
            for (int m = 0; m < 4; ++m)
#pragma unroll
                for (int n = 0; n < 4; ++n)
                    acc[m][n] = __builtin_amdgcn_mfma_f32_16x16x32_bf16(af[m], bfr[n], acc[m][n], 0, 0, 0);
        }
        __builtin_amdgcn_s_setprio(0);
    }

#pragma unroll
    for (int m = 0; m < 4; ++m) {
        const int row = m0 + wr * 64 + m * 16 + lg * 4;
#pragma unroll
        for (int n = 0; n < 4; ++n) {
            const int col = n0 + wc * 64 + n * 16 + li;
            float bv = bias[col];
#pragma unroll
            for (int r2 = 0; r2 < 4; ++r2) {
                float v = acc[m][n][r2] + bv;
                if (!isUp) v = v / (1.f + __expf(-v));
                out[(size_t)(row + r2) * N + col] = f2bf(v);
            }
        }
    }
}

// ---------------- attention + late weight transposes fused launch (R16-proven)
struct TW4 { const float* src; u16* dst; int R, C, xt, gstart; };
struct TW4s { TW4 j[4]; };

__global__ __launch_bounds__(512)
void attn_tw(const u16* __restrict__ q, const u16* __restrict__ kv,
             const u16* __restrict__ kr, const u16* __restrict__ vt,
             u16* __restrict__ attn, TW4s tj)
{
    __shared__ __align__(16) u16 SMEM[2 * 20480 + 8 * 16 * 72];

    if (blockIdx.y >= 16) {
        u16 (*tile)[68] = reinterpret_cast<u16(*)[68]>(SMEM);
        const int g = (blockIdx.y - 16) * 16 + blockIdx.x;
        int e = 0;
#pragma unroll
        for (int i = 1; i < 4; ++i) e = (g >= tj.j[i].gstart) ? i : e;
        const float* src = tj.j[e].src;
        u16* dst = tj.j[e].dst;
        const int R = tj.j[e].R, C = tj.j[e].C, xt = tj.j[e].xt;
        const int base = (g - tj.j[e].gstart) * 8;
        const int t = threadIdx.x;
        for (int ti = 0; ti < 8; ++ti) {
            const int local = base + ti;
            const int c0 = (local % xt) * 64;
            const int r0 = (local / xt) * 64;
            __syncthreads();
#pragma unroll
            for (int i = 0; i < 2; ++i) {
                int idx = i * 512 + t;
                int r = idx >> 4, c4 = idx & 15;
                float4 v = *reinterpret_cast<const float4*>(&src[(size_t)(r0 + r) * C + c0 + c4 * 4]);
                u16x4 b; b[0] = f2bf(v.x); b[1] = f2bf(v.y); b[2] = f2bf(v.z); b[3] = f2bf(v.w);
                *reinterpret_cast<u16x4*>(&tile[r][c4 * 4]) = b;
            }
            __syncthreads();
#pragma unroll
            for (int i = 0; i < 2; ++i) {
                int idx = i * 512 + t;
                int rr = idx >> 4, k4 = idx & 15;
                u16x4 o;
#pragma unroll
                for (int j = 0; j < 4; ++j) o[j] = tile[k4 * 4 + j][rr];
                *reinterpret_cast<u16x4*>(&dst[(size_t)(c0 + rr) * R + r0 + k4 * 4]) = o;
            }
        }
        return;
    }

    u16 (*KVs)[20480] = reinterpret_cast<u16(*)[20480]>(SMEM);
    u16 (*Ps)[16][72] = reinterpret_cast<u16(*)[16][72]>(SMEM + 2 * 20480);

    const int t = threadIdx.x;
    const int lane = t & 63;
    const int w = t >> 6;
    const int li = lane & 15;
    const int lg = lane >> 4;
    const int h = blockIdx.x;
    const int b = 15 - blockIdx.y;

    const int qt = (w < 4) ? (2 * b + 1) : (2 * b);
    const int my_nkt = qt + 1;
    const int block_nkt = 2 * b + 2;
    const int wl = w & 3;
    const int qr = qt * 64 + wl * 16;
    const int qpos = qr + li;

    auto stage = [&](int buf, int k0) {
        u16* base = &KVs[buf][0];
#pragma unroll
        for (int i = 0; i < 3; ++i) {
            int g = w * 3 + i;
            int P = g * 64 + lane;
            int j = P / 24, s = P % 24;
            int c = (s & 24) | ((s ^ (j & 7)) & 7);
            const u16* src = (c < 16)
                ? kv + (size_t)(k0 + j) * (NH * 256) + h * 256 + c * 8
                : kr + (size_t)(k0 + j) * 64 + (c - 16) * 8;
            gload16(src, base + g * 512);
        }
#pragma unroll
        for (int i = 0; i < 2; ++i) {
            int g = w * 2 + i;
            int P = g * 64 + lane;
            int d = P >> 3, s8 = P & 7;
            int c = s8 ^ (d & 7);
            const u16* src = vt + (size_t)(h * 128 + d) * S_LEN + k0 + c * 8;
            gload16(src, base + 12288 + g * 512);
        }
    };

    bf16x8 qf[6];
#pragma unroll
    for (int kb = 0; kb < 6; ++kb)
        qf[kb] = *reinterpret_cast<const bf16x8*>(q + ((size_t)(qr + li) * NH + h) * 192 + kb * 32 + lg * 8);

    f32x4 oacc[8];
#pragma unroll
    for (int i = 0; i < 8; ++i) oacc[i] = f32x4{0.f, 0.f, 0.f, 0.f};
    float m_run = -INFINITY, l_run = 0.f;

    stage(0, 0);
    int buf = 0;
    const float scale = 0.07216878364870322f;

    for (int kt = 0; kt < block_nkt; ++kt) {
        const int k0 = kt << 6;
        __syncthreads();
        if (kt + 1 < block_nkt) stage(buf ^ 1, (kt + 1) << 6);

        if (kt < my_nkt) {
            const u16* bb = &KVs[buf][0];

            f32x4 sacc[4];
#pragma unroll
            for (int jt = 0; jt < 4; ++jt) sacc[jt] = f32x4{0.f, 0.f, 0.f, 0.f};
            __builtin_amdgcn_s_setprio(1);
#pragma unroll
            for (int kb = 0; kb < 6; ++kb) {
                const int c = kb * 4 + lg;
                const int s = (c & 24) | ((c ^ (li & 7)) & 7);
#pragma unroll
                for (int jt = 0; jt < 4; ++jt) {
                    bf16x8 kf = *reinterpret_cast<const bf16x8*>(bb + ((jt * 16 + li) * 24 + s) * 8);
                    sacc[jt] = __builtin_amdgcn_mfma_f32_16x16x32_bf16(kf, qf[kb], sacc[jt], 0, 0, 0);
                }
            }
            __builtin_amdgcn_s_setprio(0);

            float p[16];
            float mt = -INFINITY;
            if (k0 + 63 <= qr) {
#pragma unroll
                for (int jt = 0; jt < 4; ++jt)
#pragma unroll
                    for (int r = 0; r < 4; ++r) {
                        float sv = sacc[jt][r] * scale;
                        p[jt * 4 + r] = sv;
                        mt = fmaxf(mt, sv);
                    }
            } else {
#pragma unroll
                for (int jt = 0; jt < 4; ++jt)
#pragma unroll
                    for (int r = 0; r < 4; ++r) {
                        int jpos = k0 + jt * 16 + lg * 4 + r;
                        float sv = (jpos <= qpos) ? sacc[jt][r] * scale : -INFINITY;
                        p[jt * 4 + r] = sv;
                        mt = fmaxf(mt, sv);
                    }
            }
            mt = fmaxf(mt, __shfl_xor(mt, 16));
            mt = fmaxf(mt, __shfl_xor(mt, 32));
            if (!__all(mt <= m_run + 8.f)) {
                float mn = fmaxf(m_run, mt);
                float sf = __expf(m_run - mn);
                float sfr[4];
#pragma unroll
                for (int r = 0; r < 4; ++r)
                    sfr[r] = __shfl(sf, (lane & 48) + lg * 4 + r);
#pragma unroll
                for (int d2 = 0; d2 < 8; ++d2)
#pragma unroll
                    for (int r = 0; r < 4; ++r)
                        oacc[d2][r] *= sfr[r];
                l_run *= sf;
                m_run = mn;
            }
            float rsum = 0.f;
#pragma unroll
            for (int i2 = 0; i2 < 16; ++i2) { p[i2] = __expf(p[i2] - m_run); rsum += p[i2]; }
            rsum += __shfl_xor(rsum, 16);
            rsum += __shfl_xor(rsum, 32);
            l_run += rsum;

#pragma unroll
            for (int jt = 0; jt < 4; ++jt) {
                u16x4 pk;
                pk[0] = f2bf(p[jt * 4 + 0]); pk[1] = f2bf(p[jt * 4 + 1]);
                pk[2] = f2bf(p[jt * 4 + 2]); pk[3] = f2bf(p[jt * 4 + 3]);
                *reinterpret_cast<u16x4*>(&Ps[w][li][jt * 16 + lg * 4]) = pk;
            }

            __builtin_amdgcn_s_setprio(1);
#pragma unroll
            for (int ks = 0; ks < 2; ++ks) {
                bf16x8 pf = *reinterpret_cast<const bf16x8*>(&Ps[w][li][ks * 32 + lg * 8]);
                const int vs = (ks * 4 + lg) ^ (li & 7);
#pragma unroll
                for (int d2 = 0; d2 < 8; ++d2) {
                    bf16x8 vf = *reinterpret_cast<const bf16x8*>(bb + 12288 + ((d2 * 16 + li) * 8 + vs) * 8);
                    oacc[d2] = __builtin_amdgcn_mfma_f32_16x16x32_bf16(pf, vf, oacc[d2], 0, 0, 0);
                }
            }
            __builtin_amdgcn_s_setprio(0);
        }
        buf ^= 1;
    }

    float rl = 1.f / l_run;
    float rlr[4];
#pragma unroll
    for (int r = 0; r < 4; ++r)
        rlr[r] = __shfl(rl, (lane & 48) + lg * 4 + r);
#pragma unroll
    for (int d2 = 0; d2 < 8; ++d2)
#pragma unroll
        for (int r = 0; r < 4; ++r) {
            int srow = qr + lg * 4 + r;
            int dcol = d2 * 16 + li;
            attn[(size_t)srow * (NH * DVAL) + h * DVAL + dcol] = f2bf(oacc[d2][r] * rlr[r]);
        }
}

// ---------------- host side
extern "C" void kernel_launch(void* const* d_in, const int* in_sizes, int n_in,
                              void* d_out, int out_size, void* d_ws, size_t ws_size,
                              hipStream_t stream)
{
    const float* hidden   = (const float*)d_in[0];
    const float* pa_scale = (const float*)d_in[2];
    const float* wqa      = (const float*)d_in[3];
    const float* qn_scale = (const float*)d_in[4];
    const float* wqb      = (const float*)d_in[5];
    const float* wkva     = (const float*)d_in[6];
    const float* kv_scale = (const float*)d_in[7];
    const float* wkvb     = (const float*)d_in[8];
    const float* wo       = (const float*)d_in[9];
    const float* pf_scale = (const float*)d_in[10];
    const float* wg       = (const float*)d_in[11];
    const float* bg       = (const float*)d_in[12];
    const float* wu       = (const float*)d_in[13];
    const float* bu       = (const float*)d_in[14];
    const float* wd       = (const float*)d_in[15];
    const float* bd       = (const float*)d_in[16];
    float* out = (float*)d_out;

    size_t off = 0;
    auto alloc = [&](size_t bytes) {
        off = (off + 255) & ~(size_t)255;
        void* p = (char*)d_ws + off;
        off += bytes;
        return p;
    };
    u16* wqaT  = (u16*)alloc((size_t)QLR * DM * 2);
    u16* wqbT  = (u16*)alloc((size_t)3072 * QLR * 2);
    u16* wkvaT = (u16*)alloc((size_t)640 * DM * 2);
    u16* wkvbT = (u16*)alloc((size_t)4096 * KVLR * 2);
    u16* woT   = (u16*)alloc((size_t)DM * DM * 2);
    u16* wgT   = (u16*)alloc((size_t)FFD * DM * 2);
    u16* wuT   = (u16*)alloc((size_t)FFD * DM * 2);
    u16* wdT   = (u16*)alloc((size_t)DM * FFD * 2);
    u16* n1    = (u16*)alloc((size_t)S_LEN * DM * 2);
    float* qlora32 = (float*)alloc((size_t)S_LEN * QLR * 4);
    float* kva32   = (float*)alloc((size_t)S_LEN * 576 * 4);
    u16* qn    = (u16*)alloc((size_t)S_LEN * QLR * 2);
    u16* qbuf  = (u16*)alloc((size_t)S_LEN * 3072 * 2);
    u16* ckvn  = (u16*)alloc((size_t)S_LEN * KVLR * 2);
    u16* kvbuf = (u16*)alloc((size_t)S_LEN * 4096 * 2);
    u16* krbuf = (u16*)alloc((size_t)S_LEN * 64 * 2);
    u16* attnb = (u16*)alloc((size_t)S_LEN * DM * 2);
    float* x2  = (float*)alloc((size_t)S_LEN * DM * 4);
    u16* n2    = (u16*)alloc((size_t)S_LEN * DM * 2);
    u16* gbuf  = (u16*)alloc((size_t)S_LEN * FFD * 2);
    u16* hbuf  = (u16*)alloc((size_t)S_LEN * FFD * 2);   // unused (kept for layout stability)
    u16* vtb  = (u16*)qlora32;
    u16* ubuf = (u16*)qlora32;
    (void)ws_size; (void)in_sizes; (void)n_in; (void)out_size; (void)hbuf;

    TWJobs ejobs;
    int startAcc = 0;
    auto setE = [&](int i, const float* s, u16* d, int R, int C) {
        ejobs.j[i] = TWJob{s, d, R, C, C / 64, startAcc};
        startAcc += (C / 64) * (R / 64);
    };
    setE(0, wqa,  wqaT,  2048, 1536);
    setE(1, wqb,  wqbT,  1536, 3072);
    setE(2, wkva, wkvaT, 2048,  576);
    setE(3, wkvb, wkvbT,  512, 4096);
    hipLaunchKernelGGL(transpose_all, dim3(startAcc), 256, 0, stream, ejobs);

    hipMemsetAsync(qlora32, 0, (size_t)S_LEN * QLR * 4, stream);
    hipMemsetAsync(kva32,   0, (size_t)S_LEN * 576 * 4, stream);

    // pre-attn norm + x2 = hidden copy (replaces rms_norm + hipMemcpyAsync)
    hipLaunchKernelGGL(rms_norm_copy, dim3(S_LEN), 256, 0, stream, hidden, DM, pa_scale, n1, x2);

    {
        GJob jqa  {n1, wqaT,  qlora32, QLR, DM, 12, 2};
        GJob jkva {n1, wkvaT, kva32,   576, DM,  5, 4};
        hipLaunchKernelGGL((gemm_bt2<5>), dim3(16, 44), 256, 0, stream, jqa, jkva);
    }
    hipLaunchKernelGGL(rms_norm2, dim3(S_LEN, 2), 256, 0, stream,
                       qlora32, QLR, QLR, qn_scale, qn, QLR,
                       kva32, 576, KVLR, kv_scale, ckvn, KVLR);
    {
        BJob jqb  {qn,   wqbT,  qbuf,  3072, QLR,  24};
        BJob jkvb {ckvn, wkvbT, kvbuf, 4096, KVLR, 32};
        hipLaunchKernelGGL(gemm_big2, dim3(8, 56), 512, 0, stream, jqb, jkvb);
    }
    hipLaunchKernelGGL(rope_tv, dim3(S_LEN + 1024), 256, 0, stream, qbuf, kva32, krbuf, kvbuf, vtb);

    TW4s tj;
    int gAcc = 0;
    auto setL = [&](int i, const float* s, u16* d, int R, int C) {
        tj.j[i] = TW4{s, d, R, C, C / 64, gAcc};
        gAcc += (C / 64) * (R / 64) / 8;
    };
    setL(0, wo, woT, 2048, 2048);
    setL(1, wg, wgT, 2048, 8192);
    setL(2, wu, wuT, 2048, 8192);
    setL(3, wd, wdT, 8192, 2048);
    hipLaunchKernelGGL(attn_tw, dim3(16, 16 + 104), 512, 0, stream, qbuf, kvbuf, krbuf, vtb, attnb, tj);

    hipLaunchKernelGGL((gemm_big<5>), dim3(8, 16, 4), 512, 0, stream, attnb, woT, x2, S_LEN, DM, DM, nullptr, nullptr);

    // pre-ffn norm + out = x2 + bd (replaces rms_norm + init_out)
    hipLaunchKernelGGL(rms_norm_bias, dim3(S_LEN), 256, 0, stream, x2, DM, pf_scale, n2, bd, out);

    hipLaunchKernelGGL(gemm_gu, dim3(8, 64, 2), 512, 0, stream, n2, wgT, wuT, gbuf, ubuf, S_LEN, FFD, DM, bg, bu);
    // wd with fused A = gbuf * ubuf (silu already applied to gbuf)
    hipLaunchKernelGGL(gemm_wd, dim3(8, 16, 4), 512, 0, stream, gbuf, ubuf, wdT, out, S_LEN, DM, FFD);
}

// Round 20
// 587.764 us; speedup vs baseline: 1.0343x; 1.0343x over previous
//
#include <hip/hip_runtime.h>
#include <hip/hip_bf16.h>
#include <stdint.h>

typedef unsigned short u16;
using f32x4  = __attribute__((ext_vector_type(4))) float;
using bf16x8 = __attribute__((ext_vector_type(8))) __bf16;
using u32x4  = __attribute__((ext_vector_type(4))) uint32_t;
using u16x4  = __attribute__((ext_vector_type(4))) unsigned short;
using u16x8  = __attribute__((ext_vector_type(8))) unsigned short;

#define S_LEN 2048
#define DM    2048
#define NH    16
#define QLR   1536
#define KVLR  512
#define DNOPE 128
#define DROPE 64
#define DVAL  128
#define FFD   8192

static __device__ __forceinline__ float bf2f(u16 u) {
    union { uint32_t i; float f; } v; v.i = ((uint32_t)u) << 16; return v.f;
}
static __device__ __forceinline__ u16 f2bf(float f) {
    union { float f; uint32_t i; } v; v.f = f;
    uint32_t x = v.i;
    return (u16)((x + 0x7FFF + ((x >> 16) & 1)) >> 16);  // RNE
}
static __device__ __forceinline__ void gload16(const u16* g, const u16* l) {
    __builtin_amdgcn_global_load_lds(
        (const __attribute__((address_space(1))) void*)g,
        (__attribute__((address_space(3))) void*)l, 16, 0, 0);
}

// ---------------- weight transposes (early: 4 jobs, one launch)
struct TWJob { const float* src; u16* dst; int R, C, xt, start; };
struct TWJobs { TWJob j[4]; };

__global__ __launch_bounds__(256)
void transpose_all(TWJobs jobs)
{
    __shared__ __align__(16) u16 tile[64][68];
    const int bid = blockIdx.x;
    int e = 0;
#pragma unroll
    for (int i = 1; i < 4; ++i) e = (bid >= jobs.j[i].start) ? i : e;
    const float* src = jobs.j[e].src;
    u16* dst = jobs.j[e].dst;
    const int R = jobs.j[e].R, C = jobs.j[e].C;
    const int local = bid - jobs.j[e].start;
    const int c0 = (local % jobs.j[e].xt) * 64;
    const int r0 = (local / jobs.j[e].xt) * 64;
    const int t = threadIdx.x;
#pragma unroll
    for (int i = 0; i < 4; ++i) {
        int idx = i * 256 + t;
        int r = idx >> 4, c4 = idx & 15;
        float4 v = *reinterpret_cast<const float4*>(&src[(size_t)(r0 + r) * C + c0 + c4 * 4]);
        u16x4 b; b[0] = f2bf(v.x); b[1] = f2bf(v.y); b[2] = f2bf(v.z); b[3] = f2bf(v.w);
        *reinterpret_cast<u16x4*>(&tile[r][c4 * 4]) = b;
    }
    __syncthreads();
#pragma unroll
    for (int i = 0; i < 4; ++i) {
        int idx = i * 256 + t;
        int rr = idx >> 4, k4 = idx & 15;
        u16x4 o;
#pragma unroll
        for (int j = 0; j < 4; ++j) o[j] = tile[k4 * 4 + j][rr];
        *reinterpret_cast<u16x4*>(&dst[(size_t)(c0 + rr) * R + r0 + k4 * 4]) = o;
    }
}

// ---------------- RMS norm + f32 copy of input (x2 = in)
__global__ __launch_bounds__(256)
void rms_norm_copy(const float* __restrict__ in, int width,
                   const float* __restrict__ scale, u16* __restrict__ out,
                   float* __restrict__ copy_out)
{
    const int row = blockIdx.x;
    const int t = threadIdx.x;
    float ss = 0.f;
    for (int c = t; c < width; c += 256) {
        float v = in[(size_t)row * width + c];
        ss += v * v;
    }
#pragma unroll
    for (int o = 32; o > 0; o >>= 1) ss += __shfl_xor(ss, o);
    __shared__ float red[4];
    if ((t & 63) == 0) red[t >> 6] = ss;
    __syncthreads();
    float inv = rsqrtf((red[0] + red[1] + red[2] + red[3]) / (float)width + 1e-6f);
    for (int c = t; c < width; c += 256) {
        float v = in[(size_t)row * width + c];
        out[(size_t)row * width + c] = f2bf(v * inv * scale[c]);
        copy_out[(size_t)row * width + c] = v;
    }
}

// ---------------- RMS norm + bias epilogue (outf = in + bd): pre-ffn
__global__ __launch_bounds__(256)
void rms_norm_bias(const float* __restrict__ in, int width,
                   const float* __restrict__ scale, u16* __restrict__ out,
                   const float* __restrict__ bd, float* __restrict__ outf)
{
    const int row = blockIdx.x;
    const int t = threadIdx.x;
    float ss = 0.f;
    for (int c = t; c < width; c += 256) {
        float v = in[(size_t)row * width + c];
        ss += v * v;
    }
#pragma unroll
    for (int o = 32; o > 0; o >>= 1) ss += __shfl_xor(ss, o);
    __shared__ float red[4];
    if ((t & 63) == 0) red[t >> 6] = ss;
    __syncthreads();
    float inv = rsqrtf((red[0] + red[1] + red[2] + red[3]) / (float)width + 1e-6f);
    for (int c = t; c < width; c += 256) {
        float v = in[(size_t)row * width + c];
        out[(size_t)row * width + c] = f2bf(v * inv * scale[c]);
        outf[(size_t)row * width + c] = v + bd[c];
    }
}

// ---------------- dual RMS norm (f32 in): y selects job
__global__ __launch_bounds__(256)
void rms_norm2(const float* __restrict__ inA, int strideA, int widthA,
               const float* __restrict__ scaleA, u16* __restrict__ outA, int ostrA,
               const float* __restrict__ inB, int strideB, int widthB,
               const float* __restrict__ scaleB, u16* __restrict__ outB, int ostrB)
{
    const float* in   = blockIdx.y ? inB : inA;
    const float* scale= blockIdx.y ? scaleB : scaleA;
    u16* out          = blockIdx.y ? outB : outA;
    const int stride  = blockIdx.y ? strideB : strideA;
    const int width   = blockIdx.y ? widthB : widthA;
    const int ostr    = blockIdx.y ? ostrB : ostrA;
    const int row = blockIdx.x;
    const int t = threadIdx.x;
    float ss = 0.f;
    for (int c = t; c < width; c += 256) {
        float v = in[(size_t)row * stride + c];
        ss += v * v;
    }
#pragma unroll
    for (int o = 32; o > 0; o >>= 1) ss += __shfl_xor(ss, o);
    __shared__ float red[4];
    if ((t & 63) == 0) red[t >> 6] = ss;
    __syncthreads();
    float inv = rsqrtf((red[0] + red[1] + red[2] + red[3]) / (float)width + 1e-6f);
    for (int c = t; c < width; c += 256) {
        float v = in[(size_t)row * stride + c];
        out[(size_t)row * ostr + c] = f2bf(v * inv * scale[c]);
    }
}

// ---------------- RoPE + V-transpose merged
__global__ __launch_bounds__(256)
void rope_tv(u16* __restrict__ q, const float* __restrict__ kva, u16* __restrict__ kr,
             const u16* __restrict__ kv, u16* __restrict__ vt)
{
    const int bid = blockIdx.x;
    const int t = threadIdx.x;
    if (bid < S_LEN) {
        const int s = bid;
        for (int idx = t; idx < 544; idx += 256) {
            int d = idx & 31;
            float invf = powf(10000.f, -(float)(2 * d) / 64.f);
            float ang = (float)s * invf;
            float cs = cosf(ang), sn = sinf(ang);
            if (idx < 512) {
                int hh = idx >> 5;
                u16* base = q + ((size_t)s * NH + hh) * 192 + 128;
                float x1 = bf2f(base[d]), x2 = bf2f(base[d + 32]);
                base[d]      = f2bf(x1 * cs - x2 * sn);
                base[d + 32] = f2bf(x2 * cs + x1 * sn);
            } else {
                const float* kb = kva + (size_t)s * 576 + 512;
                float x1 = kb[d], x2 = kb[d + 32];
                kr[(size_t)s * 64 + d]      = f2bf(x1 * cs - x2 * sn);
                kr[(size_t)s * 64 + d + 32] = f2bf(x2 * cs + x1 * sn);
            }
        }
        return;
    }
    __shared__ __align__(16) u16 tile[64][76];
    const int t2 = bid - S_LEN;
    const int s0 = (t2 & 31) * 64;
    const int d0 = ((t2 >> 5) & 1) * 64;
    const int h  = t2 >> 6;
#pragma unroll
    for (int i = 0; i < 2; ++i) {
        int idx = i * 256 + t;
        int s = idx >> 3, c8 = idx & 7;
        u16x8 v = *reinterpret_cast<const u16x8*>(kv + (size_t)(s0 + s) * (NH * 256) + h * 256 + 128 + d0 + c8 * 8);
        u16x4 lo, hi;
#pragma unroll
        for (int j = 0; j < 4; ++j) { lo[j] = v[j]; hi[j] = v[4 + j]; }
        *reinterpret_cast<u16x4*>(&tile[s][c8 * 8])     = lo;
        *reinterpret_cast<u16x4*>(&tile[s][c8 * 8 + 4]) = hi;
    }
    __syncthreads();
#pragma unroll
    for (int i = 0; i < 4; ++i) {
        int idx = i * 256 + t;
        int d = idx >> 4, s4 = idx & 15;
        u16x4 o;
#pragma unroll
        for (int j = 0; j < 4; ++j) o[j] = tile[s4 * 4 + j][d];
        *reinterpret_cast<u16x4*>(&vt[(size_t)(h * 128 + d0 + d) * S_LEN + s0 + s4 * 4]) = o;
    }
}

// ---------------- elementwise: h = g * u (bf16, vectorized)
__global__ __launch_bounds__(256)
void mul_gu(const u16* __restrict__ g, const u16* __restrict__ u,
            u16* __restrict__ h, int total8)
{
    int i = blockIdx.x * 256 + threadIdx.x;
    const int stride = gridDim.x * 256;
    for (; i < total8; i += stride) {
        u16x8 gv = ((const u16x8*)g)[i];
        u16x8 uv = ((const u16x8*)u)[i];
        u16x8 hv;
#pragma unroll
        for (int j = 0; j < 8; ++j) hv[j] = f2bf(bf2f(gv[j]) * bf2f(uv[j]));
        ((u16x8*)h)[i] = hv;
    }
}

// ---------------- dual-job 128x128 BK=64 TN bf16 GEMM — qa/kva path
struct GJob { const u16* A; const u16* BT; void* out; int N, K, yCount, zCount; };

template<int EPI>
__global__ __launch_bounds__(256)
void gemm_bt2(GJob j0, GJob j1)
{
    __shared__ __align__(16) u16 As[128 * 64];
    __shared__ __align__(16) u16 Bs[128 * 64];
    const int t = threadIdx.x;
    const int lane = t & 63;
    const int w = t >> 6;
    const int wr = w >> 1, wc = w & 1;
    const int li = lane & 15;
    const int lg = lane >> 4;

    const int gx = gridDim.x;
    int nwg = gx * gridDim.y;
    int bid = blockIdx.y * gx + blockIdx.x;
    bid = (bid & 7) * (nwg >> 3) + (bid >> 3);
    const int m0 = (bid % gx) * 128;
    int yy = bid / gx;

    const int j0span = j0.yCount * j0.zCount;
    const GJob& J = (yy < j0span) ? j0 : j1;
    if (yy >= j0span) yy -= j0span;
    const int ntile = yy % J.yCount;
    const int z = yy / J.yCount;
    const int n0 = ntile * 128;
    const int N = J.N, K = J.K;

    const int nktt = K >> 6;
    const int nz = J.zCount;
    const int qq = nktt / nz, rr = nktt % nz;
    const int kt0 = z * qq + (z < rr ? z : rr);
    const int ktEnd = kt0 + qq + (z < rr ? 1 : 0);

    const int srow = w * 32 + (lane >> 3);
    const int scol = (((lane & 7) ^ (lane >> 3)) << 3);
    const u16* ag = J.A  + (size_t)(m0 + srow) * K + scol;
    const u16* bg = J.BT + (size_t)(n0 + srow) * K + scol;

    f32x4 acc[4][4];
#pragma unroll
    for (int m = 0; m < 4; ++m)
#pragma unroll
        for (int n = 0; n < 4; ++n)
            acc[m][n] = f32x4{0.f, 0.f, 0.f, 0.f};

    for (int kt = kt0; kt < ktEnd; ++kt) {
        const int k0 = kt << 6;
        __syncthreads();
#pragma unroll
        for (int i = 0; i < 4; ++i) {
            gload16(ag + (size_t)i * 8 * K + k0, As + (w * 32 + i * 8) * 64);
            gload16(bg + (size_t)i * 8 * K + k0, Bs + (w * 32 + i * 8) * 64);
        }
        __syncthreads();
#pragma unroll
        for (int kk = 0; kk < 2; ++kk) {
            const int csw = (kk * 32 + lg * 8) ^ ((li & 7) << 3);
            bf16x8 af[4], bfr[4];
#pragma unroll
            for (int m = 0; m < 4; ++m)
                af[m] = *reinterpret_cast<const bf16x8*>(As + (wr * 64 + m * 16 + li) * 64 + csw);
#pragma unroll
            for (int n = 0; n < 4; ++n)
                bfr[n] = *reinterpret_cast<const bf16x8*>(Bs + (wc * 64 + n * 16 + li) * 64 + csw);
#pragma unroll
            for (int m = 0; m < 4; ++m)
#pragma unroll
                for (int n = 0; n < 4; ++n)
                    acc[m][n] = __builtin_amdgcn_mfma_f32_16x16x32_bf16(af[m], bfr[n], acc[m][n], 0, 0, 0);
        }
    }

#pragma unroll
    for (int m = 0; m < 4; ++m) {
        const int row = m0 + wr * 64 + m * 16 + lg * 4;
#pragma unroll
        for (int n = 0; n < 4; ++n) {
            const int col = n0 + wc * 64 + n * 16 + li;
            if (col < N) {
#pragma unroll
                for (int r2 = 0; r2 < 4; ++r2) {
                    float v = acc[m][n][r2];
                    size_t idx = (size_t)(row + r2) * N + col;
                    if (EPI == 0) ((u16*)J.out)[idx] = f2bf(v);
                    else          unsafeAtomicAdd((float*)J.out + idx, v);
                }
            }
        }
    }
}

// ---------------- dual-job 256x128 BK=64 bf16 GEMM, 8 waves — qb/kvb path
struct BJob { const u16* A; const u16* BT; u16* out; int N, K, yCount; };

__global__ __launch_bounds__(512, 4)
void gemm_big2(BJob j0, BJob j1)
{
    __shared__ __align__(16) u16 As[256 * 64];
    __shared__ __align__(16) u16 Bs[128 * 64];
    const int t = threadIdx.x;
    const int lane = t & 63;
    const int w = t >> 6;
    const int wr = w >> 1, wc = w & 1;
    const int li = lane & 15;
    const int lg = lane >> 4;

    const int gx = gridDim.x;
    int nwg = gx * gridDim.y;
    int bid = blockIdx.y * gx + blockIdx.x;
    bid = (bid & 7) * (nwg >> 3) + (bid >> 3);
    const int m0 = (bid % gx) * 256;
    int yy = bid / gx;

    const BJob& J = (yy < j0.yCount) ? j0 : j1;
    if (yy >= j0.yCount) yy -= j0.yCount;
    const int n0 = yy * 128;
    const int N = J.N, K = J.K;

    const int sr = lane >> 3;
    const int scol = (((lane & 7) ^ sr) << 3);
    const u16* ag = J.A  + (size_t)(m0 + w * 8 + sr) * K + scol;
    const u16* bg = J.BT + (size_t)(n0 + w * 8 + sr) * K + scol;
    const u16* lA = As + (w * 8) * 64;
    const u16* lB = Bs + (w * 8) * 64;

    f32x4 acc[4][4];
#pragma unroll
    for (int m = 0; m < 4; ++m)
#pragma unroll
        for (int n = 0; n < 4; ++n)
            acc[m][n] = f32x4{0.f, 0.f, 0.f, 0.f};

    const int nkt = K >> 6;
    for (int kt = 0; kt < nkt; ++kt) {
        const int k0 = kt << 6;
        __syncthreads();
#pragma unroll
        for (int i = 0; i < 4; ++i)
            gload16(ag + (size_t)i * 64 * K + k0, lA + i * 64 * 64);
#pragma unroll
        for (int i = 0; i < 2; ++i)
            gload16(bg + (size_t)i * 64 * K + k0, lB + i * 64 * 64);
        __syncthreads();
        __builtin_amdgcn_s_setprio(1);
#pragma unroll
        for (int kk = 0; kk < 2; ++kk) {
            const int csw = (kk * 32 + lg * 8) ^ ((li & 7) << 3);
            bf16x8 af[4], bfr[4];
#pragma unroll
            for (int m = 0; m < 4; ++m)
                af[m] = *reinterpret_cast<const bf16x8*>(As + (wr * 64 + m * 16 + li) * 64 + csw);
#pragma unroll
            for (int n = 0; n < 4; ++n)
                bfr[n] = *reinterpret_cast<const bf16x8*>(Bs + (wc * 64 + n * 16 + li) * 64 + csw);
#pragma unroll
            for (int m = 0; m < 4; ++m)
#pragma unroll
                for (int n = 0; n < 4; ++n)
                    acc[m][n] = __builtin_amdgcn_mfma_f32_16x16x32_bf16(af[m], bfr[n], acc[m][n], 0, 0, 0);
        }
        __builtin_amdgcn_s_setprio(0);
    }

#pragma unroll
    for (int m = 0; m < 4; ++m) {
        const int row = m0 + wr * 64 + m * 16 + lg * 4;
#pragma unroll
        for (int n = 0; n < 4; ++n) {
            const int col = n0 + wc * 64 + n * 16 + li;
#pragma unroll
            for (int r2 = 0; r2 < 4; ++r2)
                J.out[(size_t)(row + r2) * N + col] = f2bf(acc[m][n][r2]);
        }
    }
}

// ---------------- 256x128 BK=64 TN bf16 GEMM, 8 waves (R9-proven): wo/wd split-K
template<int EPI>
__global__ __launch_bounds__(512, 4)
void gemm_big(const u16* __restrict__ A, const u16* __restrict__ BT,
              void* __restrict__ out, int M, int N, int K,
              const float* __restrict__ bias, const u16* __restrict__ gmul)
{
    __shared__ __align__(16) u16 As[256 * 64];
    __shared__ __align__(16) u16 Bs[128 * 64];
    const int t = threadIdx.x;
    const int lane = t & 63;
    const int w = t >> 6;
    const int wr = w >> 1, wc = w & 1;
    const int li = lane & 15;
    const int lg = lane >> 4;

    const int gx = gridDim.x;
    int nwg = gx * gridDim.y;
    int bid = blockIdx.y * gx + blockIdx.x;
    bid = (bid & 7) * (nwg >> 3) + (bid >> 3);
    const int m0 = (bid % gx) * 256;
    const int n0 = (bid / gx) * 128;

    const int nz = gridDim.z, z = blockIdx.z;
    const int nktt = K >> 6;
    const int qq = nktt / nz, rr = nktt % nz;
    const int kt0 = z * qq + (z < rr ? z : rr);
    const int ktEnd = kt0 + qq + (z < rr ? 1 : 0);

    const int sr = lane >> 3;
    const int scol = (((lane & 7) ^ sr) << 3);
    const u16* ag = A  + (size_t)(m0 + w * 8 + sr) * K + scol;
    const u16* bg = BT + (size_t)(n0 + w * 8 + sr) * K + scol;
    const u16* lA = As + (w * 8) * 64;
    const u16* lB = Bs + (w * 8) * 64;

    f32x4 acc[4][4];
#pragma unroll
    for (int m = 0; m < 4; ++m)
#pragma unroll
        for (int n = 0; n < 4; ++n)
            acc[m][n] = f32x4{0.f, 0.f, 0.f, 0.f};

    for (int kt = kt0; kt < ktEnd; ++kt) {
        const int k0 = kt << 6;
        __syncthreads();
#pragma unroll
        for (int i = 0; i < 4; ++i)
            gload16(ag + (size_t)i * 64 * K + k0, lA + i * 64 * 64);
#pragma unroll
        for (int i = 0; i < 2; ++i)
            gload16(bg + (size_t)i * 64 * K + k0, lB + i * 64 * 64);
        __syncthreads();
        __builtin_amdgcn_s_setprio(1);
#pragma unroll
        for (int kk = 0; kk < 2; ++kk) {
            const int csw = (kk * 32 + lg * 8) ^ ((li & 7) << 3);
            bf16x8 af[4], bfr[4];
#pragma unroll
            for (int m = 0; m < 4; ++m)
                af[m] = *reinterpret_cast<const bf16x8*>(As + (wr * 64 + m * 16 + li) * 64 + csw);
#pragma unroll
            for (int n = 0; n < 4; ++n)
                bfr[n] = *reinterpret_cast<const bf16x8*>(Bs + (wc * 64 + n * 16 + li) * 64 + csw);
#pragma unroll
            for (int m = 0; m < 4; ++m)
#pragma unroll
                for (int n = 0; n < 4; ++n)
                    acc[m][n] = __builtin_amdgcn_mfma_f32_16x16x32_bf16(af[m], bfr[n], acc[m][n], 0, 0, 0);
        }
        __builtin_amdgcn_s_setprio(0);
    }

#pragma unroll
    for (int m = 0; m < 4; ++m) {
        const int row = m0 + wr * 64 + m * 16 + lg * 4;
#pragma unroll
        for (int n = 0; n < 4; ++n) {
            const int col = n0 + wc * 64 + n * 16 + li;
#pragma unroll
            for (int r2 = 0; r2 < 4; ++r2) {
                float v = acc[m][n][r2];
                size_t idx = (size_t)(row + r2) * N + col;
                if (EPI == 0) ((u16*)out)[idx] = f2bf(v);
                else          unsafeAtomicAdd((float*)out + idx, v);
            }
        }
    }
}

// ---------------- gate+up co-scheduled GEMM (R16-proven form)
__global__ __launch_bounds__(512, 4)
void gemm_gu(const u16* __restrict__ A, const u16* __restrict__ BgT, const u16* __restrict__ BuT,
             u16* __restrict__ gout, u16* __restrict__ uout, int M, int N, int K,
             const float* __restrict__ bg, const float* __restrict__ bu)
{
    __shared__ __align__(16) u16 As[256 * 64];
    __shared__ __align__(16) u16 Bs[128 * 64];
    const int t = threadIdx.x;
    const int lane = t & 63;
    const int w = t >> 6;
    const int wr = w >> 1, wc = w & 1;
    const int li = lane & 15;
    const int lg = lane >> 4;
    const int isUp = blockIdx.z;

    const u16* BT = isUp ? BuT : BgT;
    const float* bias = isUp ? bu : bg;
    u16* out = isUp ? uout : gout;

    const int gx = gridDim.x;
    int nwg = gx * gridDim.y;
    int bid = blockIdx.y * gx + blockIdx.x;
    bid = (bid & 7) * (nwg >> 3) + (bid >> 3);
    const int m0 = (bid % gx) * 256;
    const int n0 = (bid / gx) * 128;

    const int sr = lane >> 3;
    const int scol = (((lane & 7) ^ sr) << 3);
    const u16* ag = A  + (size_t)(m0 + w * 8 + sr) * K + scol;
    const u16* bgp = BT + (size_t)(n0 + w * 8 + sr) * K + scol;
    const u16* lA = As + (w * 8) * 64;
    const u16* lB = Bs + (w * 8) * 64;

    f32x4 acc[4][4];
#pragma unroll
    for (int m = 0; m < 4; ++m)
#pragma unroll
        for (int n = 0; n < 4; ++n)
            acc[m][n] = f32x4{0.f, 0.f, 0.f, 0.f};

    const int nkt = K >> 6;
    for (int kt = 0; kt < nkt; ++kt) {
        const int k0 = kt << 6;
        __syncthreads();
#pragma unroll
        for (int i = 0; i < 4; ++i)
            gload16(ag + (size_t)i * 64 * K + k0, lA + i * 64 * 64);
#pragma unroll
        for (int i = 0; i < 2; ++i)
            gload16(bgp + (size_t)i * 64 * K + k0, lB + i * 64 * 64);
        __syncthreads();
        __builtin_amdgcn_s_setprio(1);
#pragma unroll
        for (int kk = 0; kk < 2; ++kk) {
            const int csw = (kk * 32 + lg * 8) ^ ((li & 7) << 3);
            bf16x8 af[4], bfr[4];
#pragma unroll
            for (int m = 0; m < 4; ++m)
                af[m] = *reinterpret_cast<const bf16x8*>(As + (wr * 64 + m * 16 + li) * 64 + csw);
#pragma unroll
            for (int n = 0; n < 4; ++n)
                bfr[n] = *reinterpret_cast<const bf16x8*>(Bs + (wc * 64 + n * 16 + li) * 64 + csw);
#pragma unroll
            for (int m = 0; m < 4; ++m)
#pragma unroll
                for (int n = 0; n < 4; ++n)
                    acc[m][n] = __builtin_amdgcn_mfma_f32_16x16x32_bf16(af[m], bfr[n], acc[m][n], 0, 0, 0);
        }
        __builtin_amdgcn_s_setprio(0);
    }

#pragma unroll
    for (int m = 0; m < 4; ++m) {
        const int row = m0 + wr * 64 + m * 16 + lg * 4;
#pragma unroll
        for (int n = 0; n < 4; ++n) {
            const int col = n0 + wc * 64 + n * 16 + li;
            float bv = bias[col];
#pragma unroll
            for (int r2 = 0; r2 < 4; ++r2) {
                float v = acc[m][n][r2] + bv;
                if (!isUp) v = v / (1.f + __expf(-v));
                out[(size_t)(row + r2) * N + col] = f2bf(v);
            }
        }
    }
}

// ---------------- attention + late weight transposes fused launch (R16-proven)
struct TW4 { const float* src; u16* dst; int R, C, xt, gstart; };
struct TW4s { TW4 j[4]; };

__global__ __launch_bounds__(512)
void attn_tw(const u16* __restrict__ q, const u16* __restrict__ kv,
             const u16* __restrict__ kr, const u16* __restrict__ vt,
             u16* __restrict__ attn, TW4s tj)
{
    __shared__ __align__(16) u16 SMEM[2 * 20480 + 8 * 16 * 72];

    if (blockIdx.y >= 16) {
        u16 (*tile)[68] = reinterpret_cast<u16(*)[68]>(SMEM);
        const int g = (blockIdx.y - 16) * 16 + blockIdx.x;
        int e = 0;
#pragma unroll
        for (int i = 1; i < 4; ++i) e = (g >= tj.j[i].gstart) ? i : e;
        const float* src = tj.j[e].src;
        u16* dst = tj.j[e].dst;
        const int R = tj.j[e].R, C = tj.j[e].C, xt = tj.j[e].xt;
        const int base = (g - tj.j[e].gstart) * 8;
        const int t = threadIdx.x;
        for (int ti = 0; ti < 8; ++ti) {
            const int local = base + ti;
            const int c0 = (local % xt) * 64;
            const int r0 = (local / xt) * 64;
            __syncthreads();
#pragma unroll
            for (int i = 0; i < 2; ++i) {
                int idx = i * 512 + t;
                int r = idx >> 4, c4 = idx & 15;
                float4 v = *reinterpret_cast<const float4*>(&src[(size_t)(r0 + r) * C + c0 + c4 * 4]);
                u16x4 b; b[0] = f2bf(v.x); b[1] = f2bf(v.y); b[2] = f2bf(v.z); b[3] = f2bf(v.w);
                *reinterpret_cast<u16x4*>(&tile[r][c4 * 4]) = b;
            }
            __syncthreads();
#pragma unroll
            for (int i = 0; i < 2; ++i) {
                int idx = i * 512 + t;
                int rr = idx >> 4, k4 = idx & 15;
                u16x4 o;
#pragma unroll
                for (int j = 0; j < 4; ++j) o[j] = tile[k4 * 4 + j][rr];
                *reinterpret_cast<u16x4*>(&dst[(size_t)(c0 + rr) * R + r0 + k4 * 4]) = o;
            }
        }
        return;
    }

    u16 (*KVs)[20480] = reinterpret_cast<u16(*)[20480]>(SMEM);
    u16 (*Ps)[16][72] = reinterpret_cast<u16(*)[16][72]>(SMEM + 2 * 20480);

    const int t = threadIdx.x;
    const int lane = t & 63;
    const int w = t >> 6;
    const int li = lane & 15;
    const int lg = lane >> 4;
    const int h = blockIdx.x;
    const int b = 15 - blockIdx.y;

    const int qt = (w < 4) ? (2 * b + 1) : (2 * b);
    const int my_nkt = qt + 1;
    const int block_nkt = 2 * b + 2;
    const int wl = w & 3;
    const int qr = qt * 64 + wl * 16;
    const int qpos = qr + li;

    auto stage = [&](int buf, int k0) {
        u16* base = &KVs[buf][0];
#pragma unroll
        for (int i = 0; i < 3; ++i) {
            int g = w * 3 + i;
            int P = g * 64 + lane;
            int j = P / 24, s = P % 24;
            int c = (s & 24) | ((s ^ (j & 7)) & 7);
            const u16* src = (c < 16)
                ? kv + (size_t)(k0 + j) * (NH * 256) + h * 256 + c * 8
                : kr + (size_t)(k0 + j) * 64 + (c - 16) * 8;
            gload16(src, base + g * 512);
        }
#pragma unroll
        for (int i = 0; i < 2; ++i) {
            int g = w * 2 + i;
            int P = g * 64 + lane;
            int d = P >> 3, s8 = P & 7;
            int c = s8 ^ (d & 7);
            const u16* src = vt + (size_t)(h * 128 + d) * S_LEN + k0 + c * 8;
            gload16(src, base + 12288 + g * 512);
        }
    };

    bf16x8 qf[6];
#pragma unroll
    for (int kb = 0; kb < 6; ++kb)
        qf[kb] = *reinterpret_cast<const bf16x8*>(q + ((size_t)(qr + li) * NH + h) * 192 + kb * 32 + lg * 8);

    f32x4 oacc[8];
#pragma unroll
    for (int i = 0; i < 8; ++i) oacc[i] = f32x4{0.f, 0.f, 0.f, 0.f};
    float m_run = -INFINITY, l_run = 0.f;

    stage(0, 0);
    int buf = 0;
    const float scale = 0.07216878364870322f;

    for (int kt = 0; kt < block_nkt; ++kt) {
        const int k0 = kt << 6;
        __syncthreads();
        if (kt + 1 < block_nkt) stage(buf ^ 1, (kt + 1) << 6);

        if (kt < my_nkt) {
            const u16* bb = &KVs[buf][0];

            f32x4 sacc[4];
#pragma unroll
            for (int jt = 0; jt < 4; ++jt) sacc[jt] = f32x4{0.f, 0.f, 0.f, 0.f};
            __builtin_amdgcn_s_setprio(1);
#pragma unroll
            for (int kb = 0; kb < 6; ++kb) {
                const int c = kb * 4 + lg;
                const int s = (c & 24) | ((c ^ (li & 7)) & 7);
#pragma unroll
                for (int jt = 0; jt < 4; ++jt) {
                    bf16x8 kf = *reinterpret_cast<const bf16x8*>(bb + ((jt * 16 + li) * 24 + s) * 8);
                    sacc[jt] = __builtin_amdgcn_mfma_f32_16x16x32_bf16(kf, qf[kb], sacc[jt], 0, 0, 0);
                }
            }
            __builtin_amdgcn_s_setprio(0);

            float p[16];
            float mt = -INFINITY;
            if (k0 + 63 <= qr) {
#pragma unroll
                for (int jt = 0; jt < 4; ++jt)
#pragma unroll
                    for (int r = 0; r < 4; ++r) {
                        float sv = sacc[jt][r] * scale;
                        p[jt * 4 + r] = sv;
                        mt = fmaxf(mt, sv);
                    }
            } else {
#pragma unroll
                for (int jt = 0; jt < 4; ++jt)
#pragma unroll
                    for (int r = 0; r < 4; ++r) {
                        int jpos = k0 + jt * 16 + lg * 4 + r;
                        float sv = (jpos <= qpos) ? sacc[jt][r] * scale : -INFINITY;
                        p[jt * 4 + r] = sv;
                        mt = fmaxf(mt, sv);
                    }
            }
            mt = fmaxf(mt, __shfl_xor(mt, 16));
            mt = fmaxf(mt, __shfl_xor(mt, 32));
            if (!__all(mt <= m_run + 8.f)) {
                float mn = fmaxf(m_run, mt);
                float sf = __expf(m_run - mn);
                float sfr[4];
#pragma unroll
                for (int r = 0; r < 4; ++r)
                    sfr[r] = __shfl(sf, (lane & 48) + lg * 4 + r);
#pragma unroll
                for (int d2 = 0; d2 < 8; ++d2)
#pragma unroll
                    for (int r = 0; r < 4; ++r)
                        oacc[d2][r] *= sfr[r];
                l_run *= sf;
                m_run = mn;
            }
            float rsum = 0.f;
#pragma unroll
            for (int i2 = 0; i2 < 16; ++i2) { p[i2] = __expf(p[i2] - m_run); rsum += p[i2]; }
            rsum += __shfl_xor(rsum, 16);
            rsum += __shfl_xor(rsum, 32);
            l_run += rsum;

#pragma unroll
            for (int jt = 0; jt < 4; ++jt) {
                u16x4 pk;
                pk[0] = f2bf(p[jt * 4 + 0]); pk[1] = f2bf(p[jt * 4 + 1]);
                pk[2] = f2bf(p[jt * 4 + 2]); pk[3] = f2bf(p[jt * 4 + 3]);
                *reinterpret_cast<u16x4*>(&Ps[w][li][jt * 16 + lg * 4]) = pk;
            }

            __builtin_amdgcn_s_setprio(1);
#pragma unroll
            for (int ks = 0; ks < 2; ++ks) {
                bf16x8 pf = *reinterpret_cast<const bf16x8*>(&Ps[w][li][ks * 32 + lg * 8]);
                const int vs = (ks * 4 + lg) ^ (li & 7);
#pragma unroll
                for (int d2 = 0; d2 < 8; ++d2) {
                    bf16x8 vf = *reinterpret_cast<const bf16x8*>(bb + 12288 + ((d2 * 16 + li) * 8 + vs) * 8);
                    oacc[d2] = __builtin_amdgcn_mfma_f32_16x16x32_bf16(pf, vf, oacc[d2], 0, 0, 0);
                }
            }
            __builtin_amdgcn_s_setprio(0);
        }
        buf ^= 1;
    }

    float rl = 1.f / l_run;
    float rlr[4];
#pragma unroll
    for (int r = 0; r < 4; ++r)
        rlr[r] = __shfl(rl, (lane & 48) + lg * 4 + r);
#pragma unroll
    for (int d2 = 0; d2 < 8; ++d2)
#pragma unroll
        for (int r = 0; r < 4; ++r) {
            int srow = qr + lg * 4 + r;
            int dcol = d2 * 16 + li;
            attn[(size_t)srow * (NH * DVAL) + h * DVAL + dcol] = f2bf(oacc[d2][r] * rlr[r]);
        }
}

// ---------------- host side
extern "C" void kernel_launch(void* const* d_in, const int* in_sizes, int n_in,
                              void* d_out, int out_size, void* d_ws, size_t ws_size,
                              hipStream_t stream)
{
    const float* hidden   = (const float*)d_in[0];
    const float* pa_scale = (const float*)d_in[2];
    const float* wqa      = (const float*)d_in[3];
    const float* qn_scale = (const float*)d_in[4];
    const float* wqb      = (const float*)d_in[5];
    const float* wkva     = (const float*)d_in[6];
    const float* kv_scale = (const float*)d_in[7];
    const float* wkvb     = (const float*)d_in[8];
    const float* wo       = (const float*)d_in[9];
    const float* pf_scale = (const float*)d_in[10];
    const float* wg       = (const float*)d_in[11];
    const float* bg       = (const float*)d_in[12];
    const float* wu       = (const float*)d_in[13];
    const float* bu       = (const float*)d_in[14];
    const float* wd       = (const float*)d_in[15];
    const float* bd       = (const float*)d_in[16];
    float* out = (float*)d_out;

    size_t off = 0;
    auto alloc = [&](size_t bytes) {
        off = (off + 255) & ~(size_t)255;
        void* p = (char*)d_ws + off;
        off += bytes;
        return p;
    };
    u16* wqaT  = (u16*)alloc((size_t)QLR * DM * 2);
    u16* wqbT  = (u16*)alloc((size_t)3072 * QLR * 2);
    u16* wkvaT = (u16*)alloc((size_t)640 * DM * 2);
    u16* wkvbT = (u16*)alloc((size_t)4096 * KVLR * 2);
    u16* woT   = (u16*)alloc((size_t)DM * DM * 2);
    u16* wgT   = (u16*)alloc((size_t)FFD * DM * 2);
    u16* wuT   = (u16*)alloc((size_t)FFD * DM * 2);
    u16* wdT   = (u16*)alloc((size_t)DM * FFD * 2);
    u16* n1    = (u16*)alloc((size_t)S_LEN * DM * 2);
    float* qlora32 = (float*)alloc((size_t)S_LEN * QLR * 4);
    float* kva32   = (float*)alloc((size_t)S_LEN * 576 * 4);
    u16* qn    = (u16*)alloc((size_t)S_LEN * QLR * 2);
    u16* qbuf  = (u16*)alloc((size_t)S_LEN * 3072 * 2);
    u16* ckvn  = (u16*)alloc((size_t)S_LEN * KVLR * 2);
    u16* kvbuf = (u16*)alloc((size_t)S_LEN * 4096 * 2);
    u16* krbuf = (u16*)alloc((size_t)S_LEN * 64 * 2);
    u16* attnb = (u16*)alloc((size_t)S_LEN * DM * 2);
    float* x2  = (float*)alloc((size_t)S_LEN * DM * 4);
    u16* n2    = (u16*)alloc((size_t)S_LEN * DM * 2);
    u16* gbuf  = (u16*)alloc((size_t)S_LEN * FFD * 2);
    u16* hbuf  = (u16*)alloc((size_t)S_LEN * FFD * 2);
    u16* vtb  = (u16*)qlora32;
    u16* ubuf = (u16*)qlora32;
    (void)ws_size; (void)in_sizes; (void)n_in; (void)out_size;

    TWJobs ejobs;
    int startAcc = 0;
    auto setE = [&](int i, const float* s, u16* d, int R, int C) {
        ejobs.j[i] = TWJob{s, d, R, C, C / 64, startAcc};
        startAcc += (C / 64) * (R / 64);
    };
    setE(0, wqa,  wqaT,  2048, 1536);
    setE(1, wqb,  wqbT,  1536, 3072);
    setE(2, wkva, wkvaT, 2048,  576);
    setE(3, wkvb, wkvbT,  512, 4096);
    hipLaunchKernelGGL(transpose_all, dim3(startAcc), 256, 0, stream, ejobs);

    hipMemsetAsync(qlora32, 0, (size_t)S_LEN * QLR * 4, stream);
    hipMemsetAsync(kva32,   0, (size_t)S_LEN * 576 * 4, stream);

    // pre-attn norm + x2 = hidden copy
    hipLaunchKernelGGL(rms_norm_copy, dim3(S_LEN), 256, 0, stream, hidden, DM, pa_scale, n1, x2);

    {
        GJob jqa  {n1, wqaT,  qlora32, QLR, DM, 12, 2};
        GJob jkva {n1, wkvaT, kva32,   576, DM,  5, 4};
        hipLaunchKernelGGL((gemm_bt2<5>), dim3(16, 44), 256, 0, stream, jqa, jkva);
    }
    hipLaunchKernelGGL(rms_norm2, dim3(S_LEN, 2), 256, 0, stream,
                       qlora32, QLR, QLR, qn_scale, qn, QLR,
                       kva32, 576, KVLR, kv_scale, ckvn, KVLR);
    {
        BJob jqb  {qn,   wqbT,  qbuf,  3072, QLR,  24};
        BJob jkvb {ckvn, wkvbT, kvbuf, 4096, KVLR, 32};
        hipLaunchKernelGGL(gemm_big2, dim3(8, 56), 512, 0, stream, jqb, jkvb);
    }
    hipLaunchKernelGGL(rope_tv, dim3(S_LEN + 1024), 256, 0, stream, qbuf, kva32, krbuf, kvbuf, vtb);

    TW4s tj;
    int gAcc = 0;
    auto setL = [&](int i, const float* s, u16* d, int R, int C) {
        tj.j[i] = TW4{s, d, R, C, C / 64, gAcc};
        gAcc += (C / 64) * (R / 64) / 8;
    };
    setL(0, wo, woT, 2048, 2048);
    setL(1, wg, wgT, 2048, 8192);
    setL(2, wu, wuT, 2048, 8192);
    setL(3, wd, wdT, 8192, 2048);
    hipLaunchKernelGGL(attn_tw, dim3(16, 16 + 104), 512, 0, stream, qbuf, kvbuf, krbuf, vtb, attnb, tj);

    hipLaunchKernelGGL((gemm_big<5>), dim3(8, 16, 4), 512, 0, stream, attnb, woT, x2, S_LEN, DM, DM, nullptr, nullptr);

    // pre-ffn norm + out = x2 + bd
    hipLaunchKernelGGL(rms_norm_bias, dim3(S_LEN), 256, 0, stream, x2, DM, pf_scale, n2, bd, out);

    hipLaunchKernelGGL(gemm_gu, dim3(8, 64, 2), 512, 0, stream, n2, wgT, wuT, gbuf, ubuf, S_LEN, FFD, DM, bg, bu);
    hipLaunchKernelGGL(mul_gu, dim3(2048), 256, 0, stream, gbuf, ubuf, hbuf, S_LEN * FFD / 8);
    hipLaunchKernelGGL((gemm_big<5>), dim3(8, 16, 4), 512, 0, stream, hbuf, wdT, out, S_LEN, DM, FFD, nullptr, nullptr);
}

// Round 21
// 581.584 us; speedup vs baseline: 1.0453x; 1.0106x over previous
//
#include <hip/hip_runtime.h>
#include <hip/hip_bf16.h>
#include <stdint.h>

typedef unsigned short u16;
using f32x4  = __attribute__((ext_vector_type(4))) float;
using bf16x8 = __attribute__((ext_vector_type(8))) __bf16;
using u32x4  = __attribute__((ext_vector_type(4))) uint32_t;
using u16x4  = __attribute__((ext_vector_type(4))) unsigned short;
using u16x8  = __attribute__((ext_vector_type(8))) unsigned short;

#define S_LEN 2048
#define DM    2048
#define NH    16
#define QLR   1536
#define KVLR  512
#define DNOPE 128
#define DROPE 64
#define DVAL  128
#define FFD   8192

static __device__ __forceinline__ float bf2f(u16 u) {
    union { uint32_t i; float f; } v; v.i = ((uint32_t)u) << 16; return v.f;
}
static __device__ __forceinline__ u16 f2bf(float f) {
    union { float f; uint32_t i; } v; v.f = f;
    uint32_t x = v.i;
    return (u16)((x + 0x7FFF + ((x >> 16) & 1)) >> 16);  // RNE
}
static __device__ __forceinline__ void gload16(const u16* g, const u16* l) {
    __builtin_amdgcn_global_load_lds(
        (const __attribute__((address_space(1))) void*)g,
        (__attribute__((address_space(3))) void*)l, 16, 0, 0);
}

// ---------------- fused prologue: early weight transposes + pre-attn norm/copy + zero-fill
struct TWJob { const float* src; u16* dst; int R, C, xt, start; };
struct TWJobs { TWJob j[4]; };

__global__ __launch_bounds__(256)
void prologue_fused(TWJobs jobs, int twBlocks,
                    const float* __restrict__ hidden, const float* __restrict__ pa_scale,
                    u16* __restrict__ n1, float* __restrict__ x2,
                    float* __restrict__ z0, int z0_f4,
                    float* __restrict__ z1, int z1_f4)
{
    __shared__ __align__(16) u16 tile[64][68];
    __shared__ float red[4];
    const int bid = blockIdx.x;
    const int t = threadIdx.x;

    if (bid < twBlocks) {
        // ---- weight transpose path (wqa, wqb, wkva, wkvb)
        int e = 0;
#pragma unroll
        for (int i = 1; i < 4; ++i) e = (bid >= jobs.j[i].start) ? i : e;
        const float* src = jobs.j[e].src;
        u16* dst = jobs.j[e].dst;
        const int R = jobs.j[e].R, C = jobs.j[e].C;
        const int local = bid - jobs.j[e].start;
        const int c0 = (local % jobs.j[e].xt) * 64;
        const int r0 = (local / jobs.j[e].xt) * 64;
#pragma unroll
        for (int i = 0; i < 4; ++i) {
            int idx = i * 256 + t;
            int r = idx >> 4, c4 = idx & 15;
            float4 v = *reinterpret_cast<const float4*>(&src[(size_t)(r0 + r) * C + c0 + c4 * 4]);
            u16x4 b; b[0] = f2bf(v.x); b[1] = f2bf(v.y); b[2] = f2bf(v.z); b[3] = f2bf(v.w);
            *reinterpret_cast<u16x4*>(&tile[r][c4 * 4]) = b;
        }
        __syncthreads();
#pragma unroll
        for (int i = 0; i < 4; ++i) {
            int idx = i * 256 + t;
            int rr = idx >> 4, k4 = idx & 15;
            u16x4 o;
#pragma unroll
            for (int j = 0; j < 4; ++j) o[j] = tile[k4 * 4 + j][rr];
            *reinterpret_cast<u16x4*>(&dst[(size_t)(c0 + rr) * R + r0 + k4 * 4]) = o;
        }
        return;
    }
    if (bid < twBlocks + S_LEN) {
        // ---- pre-attn RMS norm + x2 = hidden copy
        const int row = bid - twBlocks;
        const int width = DM;
        float ss = 0.f;
        for (int c = t; c < width; c += 256) {
            float v = hidden[(size_t)row * width + c];
            ss += v * v;
        }
#pragma unroll
        for (int o = 32; o > 0; o >>= 1) ss += __shfl_xor(ss, o);
        if ((t & 63) == 0) red[t >> 6] = ss;
        __syncthreads();
        float inv = rsqrtf((red[0] + red[1] + red[2] + red[3]) / (float)width + 1e-6f);
        for (int c = t; c < width; c += 256) {
            float v = hidden[(size_t)row * width + c];
            n1[(size_t)row * width + c] = f2bf(v * inv * pa_scale[c]);
            x2[(size_t)row * width + c] = v;
        }
        return;
    }
    // ---- zero-fill path (split-K atomic targets)
    const int zb = bid - twBlocks - S_LEN;    // 0..127
    float4 z; z.x = 0.f; z.y = 0.f; z.z = 0.f; z.w = 0.f;
    if (zb < 96) {
        int i = zb * 256 + t;
        const int stride = 96 * 256;
        for (; i < z0_f4; i += stride) ((float4*)z0)[i] = z;
    } else {
        int i = (zb - 96) * 256 + t;
        const int stride = 32 * 256;
        for (; i < z1_f4; i += stride) ((float4*)z1)[i] = z;
    }
}

// ---------------- RMS norm + bias epilogue (outf = in + bd): pre-ffn
__global__ __launch_bounds__(256)
void rms_norm_bias(const float* __restrict__ in, int width,
                   const float* __restrict__ scale, u16* __restrict__ out,
                   const float* __restrict__ bd, float* __restrict__ outf)
{
    const int row = blockIdx.x;
    const int t = threadIdx.x;
    float ss = 0.f;
    for (int c = t; c < width; c += 256) {
        float v = in[(size_t)row * width + c];
        ss += v * v;
    }
#pragma unroll
    for (int o = 32; o > 0; o >>= 1) ss += __shfl_xor(ss, o);
    __shared__ float red[4];
    if ((t & 63) == 0) red[t >> 6] = ss;
    __syncthreads();
    float inv = rsqrtf((red[0] + red[1] + red[2] + red[3]) / (float)width + 1e-6f);
    for (int c = t; c < width; c += 256) {
        float v = in[(size_t)row * width + c];
        out[(size_t)row * width + c] = f2bf(v * inv * scale[c]);
        outf[(size_t)row * width + c] = v + bd[c];
    }
}

// ---------------- dual RMS norm (f32 in): y selects job
__global__ __launch_bounds__(256)
void rms_norm2(const float* __restrict__ inA, int strideA, int widthA,
               const float* __restrict__ scaleA, u16* __restrict__ outA, int ostrA,
               const float* __restrict__ inB, int strideB, int widthB,
               const float* __restrict__ scaleB, u16* __restrict__ outB, int ostrB)
{
    const float* in   = blockIdx.y ? inB : inA;
    const float* scale= blockIdx.y ? scaleB : scaleA;
    u16* out          = blockIdx.y ? outB : outA;
    const int stride  = blockIdx.y ? strideB : strideA;
    const int width   = blockIdx.y ? widthB : widthA;
    const int ostr    = blockIdx.y ? ostrB : ostrA;
    const int row = blockIdx.x;
    const int t = threadIdx.x;
    float ss = 0.f;
    for (int c = t; c < width; c += 256) {
        float v = in[(size_t)row * stride + c];
        ss += v * v;
    }
#pragma unroll
    for (int o = 32; o > 0; o >>= 1) ss += __shfl_xor(ss, o);
    __shared__ float red[4];
    if ((t & 63) == 0) red[t >> 6] = ss;
    __syncthreads();
    float inv = rsqrtf((red[0] + red[1] + red[2] + red[3]) / (float)width + 1e-6f);
    for (int c = t; c < width; c += 256) {
        float v = in[(size_t)row * stride + c];
        out[(size_t)row * ostr + c] = f2bf(v * inv * scale[c]);
    }
}

// ---------------- RoPE + V-transpose merged
__global__ __launch_bounds__(256)
void rope_tv(u16* __restrict__ q, const float* __restrict__ kva, u16* __restrict__ kr,
             const u16* __restrict__ kv, u16* __restrict__ vt)
{
    const int bid = blockIdx.x;
    const int t = threadIdx.x;
    if (bid < S_LEN) {
        const int s = bid;
        for (int idx = t; idx < 544; idx += 256) {
            int d = idx & 31;
            float invf = powf(10000.f, -(float)(2 * d) / 64.f);
            float ang = (float)s * invf;
            float cs = cosf(ang), sn = sinf(ang);
            if (idx < 512) {
                int hh = idx >> 5;
                u16* base = q + ((size_t)s * NH + hh) * 192 + 128;
                float x1 = bf2f(base[d]), x2 = bf2f(base[d + 32]);
                base[d]      = f2bf(x1 * cs - x2 * sn);
                base[d + 32] = f2bf(x2 * cs + x1 * sn);
            } else {
                const float* kb = kva + (size_t)s * 576 + 512;
                float x1 = kb[d], x2 = kb[d + 32];
                kr[(size_t)s * 64 + d]      = f2bf(x1 * cs - x2 * sn);
                kr[(size_t)s * 64 + d + 32] = f2bf(x2 * cs + x1 * sn);
            }
        }
        return;
    }
    __shared__ __align__(16) u16 tile[64][76];
    const int t2 = bid - S_LEN;
    const int s0 = (t2 & 31) * 64;
    const int d0 = ((t2 >> 5) & 1) * 64;
    const int h  = t2 >> 6;
#pragma unroll
    for (int i = 0; i < 2; ++i) {
        int idx = i * 256 + t;
        int s = idx >> 3, c8 = idx & 7;
        u16x8 v = *reinterpret_cast<const u16x8*>(kv + (size_t)(s0 + s) * (NH * 256) + h * 256 + 128 + d0 + c8 * 8);
        u16x4 lo, hi;
#pragma unroll
        for (int j = 0; j < 4; ++j) { lo[j] = v[j]; hi[j] = v[4 + j]; }
        *reinterpret_cast<u16x4*>(&tile[s][c8 * 8])     = lo;
        *reinterpret_cast<u16x4*>(&tile[s][c8 * 8 + 4]) = hi;
    }
    __syncthreads();
#pragma unroll
    for (int i = 0; i < 4; ++i) {
        int idx = i * 256 + t;
        int d = idx >> 4, s4 = idx & 15;
        u16x4 o;
#pragma unroll
        for (int j = 0; j < 4; ++j) o[j] = tile[s4 * 4 + j][d];
        *reinterpret_cast<u16x4*>(&vt[(size_t)(h * 128 + d0 + d) * S_LEN + s0 + s4 * 4]) = o;
    }
}

// ---------------- elementwise: h = g * u (bf16, vectorized)
__global__ __launch_bounds__(256)
void mul_gu(const u16* __restrict__ g, const u16* __restrict__ u,
            u16* __restrict__ h, int total8)
{
    int i = blockIdx.x * 256 + threadIdx.x;
    const int stride = gridDim.x * 256;
    for (; i < total8; i += stride) {
        u16x8 gv = ((const u16x8*)g)[i];
        u16x8 uv = ((const u16x8*)u)[i];
        u16x8 hv;
#pragma unroll
        for (int j = 0; j < 8; ++j) hv[j] = f2bf(bf2f(gv[j]) * bf2f(uv[j]));
        ((u16x8*)h)[i] = hv;
    }
}

// ---------------- dual-job 128x128 BK=64 TN bf16 GEMM — qa/kva path
struct GJob { const u16* A; const u16* BT; void* out; int N, K, yCount, zCount; };

template<int EPI>
__global__ __launch_bounds__(256)
void gemm_bt2(GJob j0, GJob j1)
{
    __shared__ __align__(16) u16 As[128 * 64];
    __shared__ __align__(16) u16 Bs[128 * 64];
    const int t = threadIdx.x;
    const int lane = t & 63;
    const int w = t >> 6;
    const int wr = w >> 1, wc = w & 1;
    const int li = lane & 15;
    const int lg = lane >> 4;

    const int gx = gridDim.x;
    int nwg = gx * gridDim.y;
    int bid = blockIdx.y * gx + blockIdx.x;
    bid = (bid & 7) * (nwg >> 3) + (bid >> 3);
    const int m0 = (bid % gx) * 128;
    int yy = bid / gx;

    const int j0span = j0.yCount * j0.zCount;
    const GJob& J = (yy < j0span) ? j0 : j1;
    if (yy >= j0span) yy -= j0span;
    const int ntile = yy % J.yCount;
    const int z = yy / J.yCount;
    const int n0 = ntile * 128;
    const int N = J.N, K = J.K;

    const int nktt = K >> 6;
    const int nz = J.zCount;
    const int qq = nktt / nz, rr = nktt % nz;
    const int kt0 = z * qq + (z < rr ? z : rr);
    const int ktEnd = kt0 + qq + (z < rr ? 1 : 0);

    const int srow = w * 32 + (lane >> 3);
    const int scol = (((lane & 7) ^ (lane >> 3)) << 3);
    const u16* ag = J.A  + (size_t)(m0 + srow) * K + scol;
    const u16* bg = J.BT + (size_t)(n0 + srow) * K + scol;

    f32x4 acc[4][4];
#pragma unroll
    for (int m = 0; m < 4; ++m)
#pragma unroll
        for (int n = 0; n < 4; ++n)
            acc[m][n] = f32x4{0.f, 0.f, 0.f, 0.f};

    for (int kt = kt0; kt < ktEnd; ++kt) {
        const int k0 = kt << 6;
        __syncthreads();
#pragma unroll
        for (int i = 0; i < 4; ++i) {
            gload16(ag + (size_t)i * 8 * K + k0, As + (w * 32 + i * 8) * 64);
            gload16(bg + (size_t)i * 8 * K + k0, Bs + (w * 32 + i * 8) * 64);
        }
        __syncthreads();
#pragma unroll
        for (int kk = 0; kk < 2; ++kk) {
            const int csw = (kk * 32 + lg * 8) ^ ((li & 7) << 3);
            bf16x8 af[4], bfr[4];
#pragma unroll
            for (int m = 0; m < 4; ++m)
                af[m] = *reinterpret_cast<const bf16x8*>(As + (wr * 64 + m * 16 + li) * 64 + csw);
#pragma unroll
            for (int n = 0; n < 4; ++n)
                bfr[n] = *reinterpret_cast<const bf16x8*>(Bs + (wc * 64 + n * 16 + li) * 64 + csw);
#pragma unroll
            for (int m = 0; m < 4; ++m)
#pragma unroll
                for (int n = 0; n < 4; ++n)
                    acc[m][n] = __builtin_amdgcn_mfma_f32_16x16x32_bf16(af[m], bfr[n], acc[m][n], 0, 0, 0);
        }
    }

#pragma unroll
    for (int m = 0; m < 4; ++m) {
        const int row = m0 + wr * 64 + m * 16 + lg * 4;
#pragma unroll
        for (int n = 0; n < 4; ++n) {
            const int col = n0 + wc * 64 + n * 16 + li;
            if (col < N) {
#pragma unroll
                for (int r2 = 0; r2 < 4; ++r2) {
                    float v = acc[m][n][r2];
                    size_t idx = (size_t)(row + r2) * N + col;
                    if (EPI == 0) ((u16*)J.out)[idx] = f2bf(v);
                    else          unsafeAtomicAdd((float*)J.out + idx, v);
                }
            }
        }
    }
}

// ---------------- dual-job 256x128 BK=64 bf16 GEMM, 8 waves — qb/kvb path
struct BJob { const u16* A; const u16* BT; u16* out; int N, K, yCount; };

__global__ __launch_bounds__(512, 4)
void gemm_big2(BJob j0, BJob j1)
{
    __shared__ __align__(16) u16 As[256 * 64];
    __shared__ __align__(16) u16 Bs[128 * 64];
    const int t = threadIdx.x;
    const int lane = t & 63;
    const int w = t >> 6;
    const int wr = w >> 1, wc = w & 1;
    const int li = lane & 15;
    const int lg = lane >> 4;

    const int gx = gridDim.x;
    int nwg = gx * gridDim.y;
    int bid = blockIdx.y * gx + blockIdx.x;
    bid = (bid & 7) * (nwg >> 3) + (bid >> 3);
    const int m0 = (bid % gx) * 256;
    int yy = bid / gx;

    const BJob& J = (yy < j0.yCount) ? j0 : j1;
    if (yy >= j0.yCount) yy -= j0.yCount;
    const int n0 = yy * 128;
    const int N = J.N, K = J.K;

    const int sr = lane >> 3;
    const int scol = (((lane & 7) ^ sr) << 3);
    const u16* ag = J.A  + (size_t)(m0 + w * 8 + sr) * K + scol;
    const u16* bg = J.BT + (size_t)(n0 + w * 8 + sr) * K + scol;
    const u16* lA = As + (w * 8) * 64;
    const u16* lB = Bs + (w * 8) * 64;

    f32x4 acc[4][4];
#pragma unroll
    for (int m = 0; m < 4; ++m)
#pragma unroll
        for (int n = 0; n < 4; ++n)
            acc[m][n] = f32x4{0.f, 0.f, 0.f, 0.f};

    const int nkt = K >> 6;
    for (int kt = 0; kt < nkt; ++kt) {
        const int k0 = kt << 6;
        __syncthreads();
#pragma unroll
        for (int i = 0; i < 4; ++i)
            gload16(ag + (size_t)i * 64 * K + k0, lA + i * 64 * 64);
#pragma unroll
        for (int i = 0; i < 2; ++i)
            gload16(bg + (size_t)i * 64 * K + k0, lB + i * 64 * 64);
        __syncthreads();
        __builtin_amdgcn_s_setprio(1);
#pragma unroll
        for (int kk = 0; kk < 2; ++kk) {
            const int csw = (kk * 32 + lg * 8) ^ ((li & 7) << 3);
            bf16x8 af[4], bfr[4];
#pragma unroll
            for (int m = 0; m < 4; ++m)
                af[m] = *reinterpret_cast<const bf16x8*>(As + (wr * 64 + m * 16 + li) * 64 + csw);
#pragma unroll
            for (int n = 0; n < 4; ++n)
                bfr[n] = *reinterpret_cast<const bf16x8*>(Bs + (wc * 64 + n * 16 + li) * 64 + csw);
#pragma unroll
            for (int m = 0; m < 4; ++m)
#pragma unroll
                for (int n = 0; n < 4; ++n)
                    acc[m][n] = __builtin_amdgcn_mfma_f32_16x16x32_bf16(af[m], bfr[n], acc[m][n], 0, 0, 0);
        }
        __builtin_amdgcn_s_setprio(0);
    }

#pragma unroll
    for (int m = 0; m < 4; ++m) {
        const int row = m0 + wr * 64 + m * 16 + lg * 4;
#pragma unroll
        for (int n = 0; n < 4; ++n) {
            const int col = n0 + wc * 64 + n * 16 + li;
#pragma unroll
            for (int r2 = 0; r2 < 4; ++r2)
                J.out[(size_t)(row + r2) * N + col] = f2bf(acc[m][n][r2]);
        }
    }
}

// ---------------- 256x128 BK=64 TN bf16 GEMM, 8 waves (R9-proven): wo/wd split-K
template<int EPI>
__global__ __launch_bounds__(512, 4)
void gemm_big(const u16* __restrict__ A, const u16* __restrict__ BT,
              void* __restrict__ out, int M, int N, int K,
              const float* __restrict__ bias, const u16* __restrict__ gmul)
{
    __shared__ __align__(16) u16 As[256 * 64];
    __shared__ __align__(16) u16 Bs[128 * 64];
    const int t = threadIdx.x;
    const int lane = t & 63;
    const int w = t >> 6;
    const int wr = w >> 1, wc = w & 1;
    const int li = lane & 15;
    const int lg = lane >> 4;

    const int gx = gridDim.x;
    int nwg = gx * gridDim.y;
    int bid = blockIdx.y * gx + blockIdx.x;
    bid = (bid & 7) * (nwg >> 3) + (bid >> 3);
    const int m0 = (bid % gx) * 256;
    const int n0 = (bid / gx) * 128;

    const int nz = gridDim.z, z = blockIdx.z;
    const int nktt = K >> 6;
    const int qq = nktt / nz, rr = nktt % nz;
    const int kt0 = z * qq + (z < rr ? z : rr);
    const int ktEnd = kt0 + qq + (z < rr ? 1 : 0);

    const int sr = lane >> 3;
    const int scol = (((lane & 7) ^ sr) << 3);
    const u16* ag = A  + (size_t)(m0 + w * 8 + sr) * K + scol;
    const u16* bg = BT + (size_t)(n0 + w * 8 + sr) * K + scol;
    const u16* lA = As + (w * 8) * 64;
    const u16* lB = Bs + (w * 8) * 64;

    f32x4 acc[4][4];
#pragma unroll
    for (int m = 0; m < 4; ++m)
#pragma unroll
        for (int n = 0; n < 4; ++n)
            acc[m][n] = f32x4{0.f, 0.f, 0.f, 0.f};

    for (int kt = kt0; kt < ktEnd; ++kt) {
        const int k0 = kt << 6;
        __syncthreads();
#pragma unroll
        for (int i = 0; i < 4; ++i)
            gload16(ag + (size_t)i * 64 * K + k0, lA + i * 64 * 64);
#pragma unroll
        for (int i = 0; i < 2; ++i)
            gload16(bg + (size_t)i * 64 * K + k0, lB + i * 64 * 64);
        __syncthreads();
        __builtin_amdgcn_s_setprio(1);
#pragma unroll
        for (int kk = 0; kk < 2; ++kk) {
            const int csw = (kk * 32 + lg * 8) ^ ((li & 7) << 3);
            bf16x8 af[4], bfr[4];
#pragma unroll
            for (int m = 0; m < 4; ++m)
                af[m] = *reinterpret_cast<const bf16x8*>(As + (wr * 64 + m * 16 + li) * 64 + csw);
#pragma unroll
            for (int n = 0; n < 4; ++n)
                bfr[n] = *reinterpret_cast<const bf16x8*>(Bs + (wc * 64 + n * 16 + li) * 64 + csw);
#pragma unroll
            for (int m = 0; m < 4; ++m)
#pragma unroll
                for (int n = 0; n < 4; ++n)
                    acc[m][n] = __builtin_amdgcn_mfma_f32_16x16x32_bf16(af[m], bfr[n], acc[m][n], 0, 0, 0);
        }
        __builtin_amdgcn_s_setprio(0);
    }

#pragma unroll
    for (int m = 0; m < 4; ++m) {
        const int row = m0 + wr * 64 + m * 16 + lg * 4;
#pragma unroll
        for (int n = 0; n < 4; ++n) {
            const int col = n0 + wc * 64 + n * 16 + li;
#pragma unroll
            for (int r2 = 0; r2 < 4; ++r2) {
                float v = acc[m][n][r2];
                size_t idx = (size_t)(row + r2) * N + col;
                if (EPI == 0) ((u16*)out)[idx] = f2bf(v);
                else          unsafeAtomicAdd((float*)out + idx, v);
            }
        }
    }
}

// ---------------- gate+up co-scheduled GEMM (R16-proven form)
__global__ __launch_bounds__(512, 4)
void gemm_gu(const u16* __restrict__ A, const u16* __restrict__ BgT, const u16* __restrict__ BuT,
             u16* __restrict__ gout, u16* __restrict__ uout, int M, int N, int K,
             const float* __restrict__ bg, const float* __restrict__ bu)
{
    __shared__ __align__(16) u16 As[256 * 64];
    __shared__ __align__(16) u16 Bs[128 * 64];
    const int t = threadIdx.x;
    const int lane = t & 63;
    const int w = t >> 6;
    const int wr = w >> 1, wc = w & 1;
    const int li = lane & 15;
    const int lg = lane >> 4;
    const int isUp = blockIdx.z;

    const u16* BT = isUp ? BuT : BgT;
    const float* bias = isUp ? bu : bg;
    u16* out = isUp ? uout : gout;

    const int gx = gridDim.x;
    int nwg = gx * gridDim.y;
    int bid = blockIdx.y * gx + blockIdx.x;
    bid = (bid & 7) * (nwg >> 3) + (bid >> 3);
    const int m0 = (bid % gx) * 256;
    const int n0 = (bid / gx) * 128;

    const int sr = lane >> 3;
    const int scol = (((lane & 7) ^ sr) << 3);
    const u16* ag = A  + (size_t)(m0 + w * 8 + sr) * K + scol;
    const u16* bgp = BT + (size_t)(n0 + w * 8 + sr) * K + scol;
    const u16* lA = As + (w * 8) * 64;
    const u16* lB = Bs + (w * 8) * 64;

    f32x4 acc[4][4];
#pragma unroll
    for (int m = 0; m < 4; ++m)
#pragma unroll
        for (int n = 0; n < 4; ++n)
            acc[m][n] = f32x4{0.f, 0.f, 0.f, 0.f};

    const int nkt = K >> 6;
    for (int kt = 0; kt < nkt; ++kt) {
        const int k0 = kt << 6;
        __syncthreads();
#pragma unroll
        for (int i = 0; i < 4; ++i)
            gload16(ag + (size_t)i * 64 * K + k0, lA + i * 64 * 64);
#pragma unroll
        for (int i = 0; i < 2; ++i)
            gload16(bgp + (size_t)i * 64 * K + k0, lB + i * 64 * 64);
        __syncthreads();
        __builtin_amdgcn_s_setprio(1);
#pragma unroll
        for (int kk = 0; kk < 2; ++kk) {
            const int csw = (kk * 32 + lg * 8) ^ ((li & 7) << 3);
            bf16x8 af[4], bfr[4];
#pragma unroll
            for (int m = 0; m < 4; ++m)
                af[m] = *reinterpret_cast<const bf16x8*>(As + (wr * 64 + m * 16 + li) * 64 + csw);
#pragma unroll
            for (int n = 0; n < 4; ++n)
                bfr[n] = *reinterpret_cast<const bf16x8*>(Bs + (wc * 64 + n * 16 + li) * 64 + csw);
#pragma unroll
            for (int m = 0; m < 4; ++m)
#pragma unroll
                for (int n = 0; n < 4; ++n)
                    acc[m][n] = __builtin_amdgcn_mfma_f32_16x16x32_bf16(af[m], bfr[n], acc[m][n], 0, 0, 0);
        }
        __builtin_amdgcn_s_setprio(0);
    }

#pragma unroll
    for (int m = 0; m < 4; ++m) {
        const int row = m0 + wr * 64 + m * 16 + lg * 4;
#pragma unroll
        for (int n = 0; n < 4; ++n) {
            const int col = n0 + wc * 64 + n * 16 + li;
            float bv = bias[col];
#pragma unroll
            for (int r2 = 0; r2 < 4; ++r2) {
                float v = acc[m][n][r2] + bv;
                if (!isUp) v = v / (1.f + __expf(-v));
                out[(size_t)(row + r2) * N + col] = f2bf(v);
            }
        }
    }
}

// ---------------- attention + late weight transposes fused launch (R16-proven)
struct TW4 { const float* src; u16* dst; int R, C, xt, gstart; };
struct TW4s { TW4 j[4]; };

__global__ __launch_bounds__(512)
void attn_tw(const u16* __restrict__ q, const u16* __restrict__ kv,
             const u16* __restrict__ kr, const u16* __restrict__ vt,
             u16* __restrict__ attn, TW4s tj)
{
    __shared__ __align__(16) u16 SMEM[2 * 20480 + 8 * 16 * 72];

    if (blockIdx.y >= 16) {
        u16 (*tile)[68] = reinterpret_cast<u16(*)[68]>(SMEM);
        const int g = (blockIdx.y - 16) * 16 + blockIdx.x;
        int e = 0;
#pragma unroll
        for (int i = 1; i < 4; ++i) e = (g >= tj.j[i].gstart) ? i : e;
        const float* src = tj.j[e].src;
        u16* dst = tj.j[e].dst;
        const int R = tj.j[e].R, C = tj.j[e].C, xt = tj.j[e].xt;
        const int base = (g - tj.j[e].gstart) * 8;
        const int t = threadIdx.x;
        for (int ti = 0; ti < 8; ++ti) {
            const int local = base + ti;
            const int c0 = (local % xt) * 64;
            const int r0 = (local / xt) * 64;
            __syncthreads();
#pragma unroll
            for (int i = 0; i < 2; ++i) {
                int idx = i * 512 + t;
                int r = idx >> 4, c4 = idx & 15;
                float4 v = *reinterpret_cast<const float4*>(&src[(size_t)(r0 + r) * C + c0 + c4 * 4]);
                u16x4 b; b[0] = f2bf(v.x); b[1] = f2bf(v.y); b[2] = f2bf(v.z); b[3] = f2bf(v.w);
                *reinterpret_cast<u16x4*>(&tile[r][c4 * 4]) = b;
            }
            __syncthreads();
#pragma unroll
            for (int i = 0; i < 2; ++i) {
                int idx = i * 512 + t;
                int rr = idx >> 4, k4 = idx & 15;
                u16x4 o;
#pragma unroll
                for (int j = 0; j < 4; ++j) o[j] = tile[k4 * 4 + j][rr];
                *reinterpret_cast<u16x4*>(&dst[(size_t)(c0 + rr) * R + r0 + k4 * 4]) = o;
            }
        }
        return;
    }

    u16 (*KVs)[20480] = reinterpret_cast<u16(*)[20480]>(SMEM);
    u16 (*Ps)[16][72] = reinterpret_cast<u16(*)[16][72]>(SMEM + 2 * 20480);

    const int t = threadIdx.x;
    const int lane = t & 63;
    const int w = t >> 6;
    const int li = lane & 15;
    const int lg = lane >> 4;
    const int h = blockIdx.x;
    const int b = 15 - blockIdx.y;

    const int qt = (w < 4) ? (2 * b + 1) : (2 * b);
    const int my_nkt = qt + 1;
    const int block_nkt = 2 * b + 2;
    const int wl = w & 3;
    const int qr = qt * 64 + wl * 16;
    const int qpos = qr + li;

    auto stage = [&](int buf, int k0) {
        u16* base = &KVs[buf][0];
#pragma unroll
        for (int i = 0; i < 3; ++i) {
            int g = w * 3 + i;
            int P = g * 64 + lane;
            int j = P / 24, s = P % 24;
            int c = (s & 24) | ((s ^ (j & 7)) & 7);
            const u16* src = (c < 16)
                ? kv + (size_t)(k0 + j) * (NH * 256) + h * 256 + c * 8
                : kr + (size_t)(k0 + j) * 64 + (c - 16) * 8;
            gload16(src, base + g * 512);
        }
#pragma unroll
        for (int i = 0; i < 2; ++i) {
            int g = w * 2 + i;
            int P = g * 64 + lane;
            int d = P >> 3, s8 = P & 7;
            int c = s8 ^ (d & 7);
            const u16* src = vt + (size_t)(h * 128 + d) * S_LEN + k0 + c * 8;
            gload16(src, base + 12288 + g * 512);
        }
    };

    bf16x8 qf[6];
#pragma unroll
    for (int kb = 0; kb < 6; ++kb)
        qf[kb] = *reinterpret_cast<const bf16x8*>(q + ((size_t)(qr + li) * NH + h) * 192 + kb * 32 + lg * 8);

    f32x4 oacc[8];
#pragma unroll
    for (int i = 0; i < 8; ++i) oacc[i] = f32x4{0.f, 0.f, 0.f, 0.f};
    float m_run = -INFINITY, l_run = 0.f;

    stage(0, 0);
    int buf = 0;
    const float scale = 0.07216878364870322f;

    for (int kt = 0; kt < block_nkt; ++kt) {
        const int k0 = kt << 6;
        __syncthreads();
        if (kt + 1 < block_nkt) stage(buf ^ 1, (kt + 1) << 6);

        if (kt < my_nkt) {
            const u16* bb = &KVs[buf][0];

            f32x4 sacc[4];
#pragma unroll
            for (int jt = 0; jt < 4; ++jt) sacc[jt] = f32x4{0.f, 0.f, 0.f, 0.f};
            __builtin_amdgcn_s_setprio(1);
#pragma unroll
            for (int kb = 0; kb < 6; ++kb) {
                const int c = kb * 4 + lg;
                const int s = (c & 24) | ((c ^ (li & 7)) & 7);
#pragma unroll
                for (int jt = 0; jt < 4; ++jt) {
                    bf16x8 kf = *reinterpret_cast<const bf16x8*>(bb + ((jt * 16 + li) * 24 + s) * 8);
                    sacc[jt] = __builtin_amdgcn_mfma_f32_16x16x32_bf16(kf, qf[kb], sacc[jt], 0, 0, 0);
                }
            }
            __builtin_amdgcn_s_setprio(0);

            float p[16];
            float mt = -INFINITY;
            if (k0 + 63 <= qr) {
#pragma unroll
                for (int jt = 0; jt < 4; ++jt)
#pragma unroll
                    for (int r = 0; r < 4; ++r) {
                        float sv = sacc[jt][r] * scale;
                        p[jt * 4 + r] = sv;
                        mt = fmaxf(mt, sv);
                    }
            } else {
#pragma unroll
                for (int jt = 0; jt < 4; ++jt)
#pragma unroll
                    for (int r = 0; r < 4; ++r) {
                        int jpos = k0 + jt * 16 + lg * 4 + r;
                        float sv = (jpos <= qpos) ? sacc[jt][r] * scale : -INFINITY;
                        p[jt * 4 + r] = sv;
                        mt = fmaxf(mt, sv);
                    }
            }
            mt = fmaxf(mt, __shfl_xor(mt, 16));
            mt = fmaxf(mt, __shfl_xor(mt, 32));
            if (!__all(mt <= m_run + 8.f)) {
                float mn = fmaxf(m_run, mt);
                float sf = __expf(m_run - mn);
                float sfr[4];
#pragma unroll
                for (int r = 0; r < 4; ++r)
                    sfr[r] = __shfl(sf, (lane & 48) + lg * 4 + r);
#pragma unroll
                for (int d2 = 0; d2 < 8; ++d2)
#pragma unroll
                    for (int r = 0; r < 4; ++r)
                        oacc[d2][r] *= sfr[r];
                l_run *= sf;
                m_run = mn;
            }
            float rsum = 0.f;
#pragma unroll
            for (int i2 = 0; i2 < 16; ++i2) { p[i2] = __expf(p[i2] - m_run); rsum += p[i2]; }
            rsum += __shfl_xor(rsum, 16);
            rsum += __shfl_xor(rsum, 32);
            l_run += rsum;

#pragma unroll
            for (int jt = 0; jt < 4; ++jt) {
                u16x4 pk;
                pk[0] = f2bf(p[jt * 4 + 0]); pk[1] = f2bf(p[jt * 4 + 1]);
                pk[2] = f2bf(p[jt * 4 + 2]); pk[3] = f2bf(p[jt * 4 + 3]);
                *reinterpret_cast<u16x4*>(&Ps[w][li][jt * 16 + lg * 4]) = pk;
            }

            __builtin_amdgcn_s_setprio(1);
#pragma unroll
            for (int ks = 0; ks < 2; ++ks) {
                bf16x8 pf = *reinterpret_cast<const bf16x8*>(&Ps[w][li][ks * 32 + lg * 8]);
                const int vs = (ks * 4 + lg) ^ (li & 7);
#pragma unroll
                for (int d2 = 0; d2 < 8; ++d2) {
                    bf16x8 vf = *reinterpret_cast<const bf16x8*>(bb + 12288 + ((d2 * 16 + li) * 8 + vs) * 8);
                    oacc[d2] = __builtin_amdgcn_mfma_f32_16x16x32_bf16(pf, vf, oacc[d2], 0, 0, 0);
                }
            }
            __builtin_amdgcn_s_setprio(0);
        }
        buf ^= 1;
    }

    float rl = 1.f / l_run;
    float rlr[4];
#pragma unroll
    for (int r = 0; r < 4; ++r)
        rlr[r] = __shfl(rl, (lane & 48) + lg * 4 + r);
#pragma unroll
    for (int d2 = 0; d2 < 8; ++d2)
#pragma unroll
        for (int r = 0; r < 4; ++r) {
            int srow = qr + lg * 4 + r;
            int dcol = d2 * 16 + li;
            attn[(size_t)srow * (NH * DVAL) + h * DVAL + dcol] = f2bf(oacc[d2][r] * rlr[r]);
        }
}

// ---------------- host side
extern "C" void kernel_launch(void* const* d_in, const int* in_sizes, int n_in,
                              void* d_out, int out_size, void* d_ws, size_t ws_size,
                              hipStream_t stream)
{
    const float* hidden   = (const float*)d_in[0];
    const float* pa_scale = (const float*)d_in[2];
    const float* wqa      = (const float*)d_in[3];
    const float* qn_scale = (const float*)d_in[4];
    const float* wqb      = (const float*)d_in[5];
    const float* wkva     = (const float*)d_in[6];
    const float* kv_scale = (const float*)d_in[7];
    const float* wkvb     = (const float*)d_in[8];
    const float* wo       = (const float*)d_in[9];
    const float* pf_scale = (const float*)d_in[10];
    const float* wg       = (const float*)d_in[11];
    const float* bg       = (const float*)d_in[12];
    const float* wu       = (const float*)d_in[13];
    const float* bu       = (const float*)d_in[14];
    const float* wd       = (const float*)d_in[15];
    const float* bd       = (const float*)d_in[16];
    float* out = (float*)d_out;

    size_t off = 0;
    auto alloc = [&](size_t bytes) {
        off = (off + 255) & ~(size_t)255;
        void* p = (char*)d_ws + off;
        off += bytes;
        return p;
    };
    u16* wqaT  = (u16*)alloc((size_t)QLR * DM * 2);
    u16* wqbT  = (u16*)alloc((size_t)3072 * QLR * 2);
    u16* wkvaT = (u16*)alloc((size_t)640 * DM * 2);
    u16* wkvbT = (u16*)alloc((size_t)4096 * KVLR * 2);
    u16* woT   = (u16*)alloc((size_t)DM * DM * 2);
    u16* wgT   = (u16*)alloc((size_t)FFD * DM * 2);
    u16* wuT   = (u16*)alloc((size_t)FFD * DM * 2);
    u16* wdT   = (u16*)alloc((size_t)DM * FFD * 2);
    u16* n1    = (u16*)alloc((size_t)S_LEN * DM * 2);
    float* qlora32 = (float*)alloc((size_t)S_LEN * QLR * 4);
    float* kva32   = (float*)alloc((size_t)S_LEN * 576 * 4);
    u16* qn    = (u16*)alloc((size_t)S_LEN * QLR * 2);
    u16* qbuf  = (u16*)alloc((size_t)S_LEN * 3072 * 2);
    u16* ckvn  = (u16*)alloc((size_t)S_LEN * KVLR * 2);
    u16* kvbuf = (u16*)alloc((size_t)S_LEN * 4096 * 2);
    u16* krbuf = (u16*)alloc((size_t)S_LEN * 64 * 2);
    u16* attnb = (u16*)alloc((size_t)S_LEN * DM * 2);
    float* x2  = (float*)alloc((size_t)S_LEN * DM * 4);
    u16* n2    = (u16*)alloc((size_t)S_LEN * DM * 2);
    u16* gbuf  = (u16*)alloc((size_t)S_LEN * FFD * 2);
    u16* hbuf  = (u16*)alloc((size_t)S_LEN * FFD * 2);
    u16* vtb  = (u16*)qlora32;
    u16* ubuf = (u16*)qlora32;
    (void)ws_size; (void)in_sizes; (void)n_in; (void)out_size;

    // fused prologue: early transposes + pre-attn norm/copy + zero split-K targets
    TWJobs ejobs;
    int startAcc = 0;
    auto setE = [&](int i, const float* s, u16* d, int R, int C) {
        ejobs.j[i] = TWJob{s, d, R, C, C / 64, startAcc};
        startAcc += (C / 64) * (R / 64);
    };
    setE(0, wqa,  wqaT,  2048, 1536);
    setE(1, wqb,  wqbT,  1536, 3072);
    setE(2, wkva, wkvaT, 2048,  576);
    setE(3, wkvb, wkvbT,  512, 4096);
    hipLaunchKernelGGL(prologue_fused, dim3(startAcc + S_LEN + 128), 256, 0, stream,
                       ejobs, startAcc, hidden, pa_scale, n1, x2,
                       qlora32, S_LEN * QLR / 4, kva32, S_LEN * 576 / 4);

    {
        GJob jqa  {n1, wqaT,  qlora32, QLR, DM, 12, 2};
        GJob jkva {n1, wkvaT, kva32,   576, DM,  5, 4};
        hipLaunchKernelGGL((gemm_bt2<5>), dim3(16, 44), 256, 0, stream, jqa, jkva);
    }
    hipLaunchKernelGGL(rms_norm2, dim3(S_LEN, 2), 256, 0, stream,
                       qlora32, QLR, QLR, qn_scale, qn, QLR,
                       kva32, 576, KVLR, kv_scale, ckvn, KVLR);
    {
        BJob jqb  {qn,   wqbT,  qbuf,  3072, QLR,  24};
        BJob jkvb {ckvn, wkvbT, kvbuf, 4096, KVLR, 32};
        hipLaunchKernelGGL(gemm_big2, dim3(8, 56), 512, 0, stream, jqb, jkvb);
    }
    hipLaunchKernelGGL(rope_tv, dim3(S_LEN + 1024), 256, 0, stream, qbuf, kva32, krbuf, kvbuf, vtb);

    TW4s tj;
    int gAcc = 0;
    auto setL = [&](int i, const float* s, u16* d, int R, int C) {
        tj.j[i] = TW4{s, d, R, C, C / 64, gAcc};
        gAcc += (C / 64) * (R / 64) / 8;
    };
    setL(0, wo, woT, 2048, 2048);
    setL(1, wg, wgT, 2048, 8192);
    setL(2, wu, wuT, 2048, 8192);
    setL(3, wd, wdT, 8192, 2048);
    hipLaunchKernelGGL(attn_tw, dim3(16, 16 + 104), 512, 0, stream, qbuf, kvbuf, krbuf, vtb, attnb, tj);

    hipLaunchKernelGGL((gemm_big<5>), dim3(8, 16, 4), 512, 0, stream, attnb, woT, x2, S_LEN, DM, DM, nullptr, nullptr);

    hipLaunchKernelGGL(rms_norm_bias, dim3(S_LEN), 256, 0, stream, x2, DM, pf_scale, n2, bd, out);

    hipLaunchKernelGGL(gemm_gu, dim3(8, 64, 2), 512, 0, stream, n2, wgT, wuT, gbuf, ubuf, S_LEN, FFD, DM, bg, bu);
    hipLaunchKernelGGL(mul_gu, dim3(2048), 256, 0, stream, gbuf, ubuf, hbuf, S_LEN * FFD / 8);
    hipLaunchKernelGGL((gemm_big<5>), dim3(8, 16, 4), 512, 0, stream, hbuf, wdT, out, S_LEN, DM, FFD, nullptr, nullptr);
}